// Round 9
// baseline (670.131 us; speedup 1.0000x reference)
//
#include <hip/hip_runtime.h>
#include <hip/hip_bf16.h>
#include <math.h>

#define N_NODES 100000
#define E_EDGES 3200000
#define K_HOPS  10
#define NPP     256                          // nodes per partition (dst>>8)
#define NPART   ((N_NODES + NPP - 1) / NPP)  // 391 partitions
#define CHUNK   4096                         // edges per scatter block
#define EPT     (CHUNK / 256)                // 16 edges per thread
#define NCHUNK  ((E_EDGES + CHUNK - 1) / CHUNK)   // 782 chunks
#define NFLAT   (NPART * NCHUNK)                  // 305762
#define SSEG    8192
#define GA      ((NFLAT + SSEG - 1) / SSEG)       // 38 scan blocks

typedef __attribute__((ext_vector_type(8))) short short8;
typedef __attribute__((ext_vector_type(4))) float floatx4;

__device__ __forceinline__ ushort f2bf(float f) {
    uint u = __float_as_uint(f);
    u += 0x7fffu + ((u >> 16) & 1u);
    return (ushort)(u >> 16);
}
__device__ __forceinline__ uint pk2(float a, float b) {
    return (uint)f2bf(a) | ((uint)f2bf(b) << 16);
}
__device__ __forceinline__ float bflo(uint u) { return __uint_as_float(u << 16); }
__device__ __forceinline__ float bfhi(uint u) { return __uint_as_float(u & 0xffff0000u); }

// ---------------------------------------------------------------------------
// Fused 3-layer MLP (256->128->128->16, relu). Writes bf16 h3 -> hops[0].
// One block = 128 rows, 4 waves x 32 rows. h1/h2 never leave LDS.
// Layer-1 A prefetched into 64 bf16 VGPRs; (256,2) launch bounds REQUIRED:
// (256,3)'s ~168-VGPR cap (r1/r2) and (256,4)'s 128 cap (r7) both spilled
// the prefetch to scratch (+11..51MB WRITE_SIZE, dur 90-121us). This
// 128-row/(256,2) version is the verified optimum: 64us, VGPR=124,
// WRITE_SIZE ideal. DO NOT re-tune occupancy here.
// LDS tiles XOR-swizzled: col ^= (row&7)<<3 (ushort units, 16B groups).
// ---------------------------------------------------------------------------
__global__ __launch_bounds__(256, 2) void fused_mlp(
    const float* __restrict__ X,
    const float* __restrict__ W1, const float* __restrict__ B1,
    const float* __restrict__ W2, const float* __restrict__ B2,
    const float* __restrict__ W3, const float* __restrict__ B3,
    ushort* __restrict__ H0)      // hops[0]: N x 16 bf16
{
    __shared__ ushort Wl[128 * 64];    // 16 KB: W slice (128 rows x 64 cols bf16)
    __shared__ ushort Hb[128 * 128];   // 32 KB: h tile  (128 rows x 128 cols bf16)

    const int t    = threadIdx.x;
    const int w    = t >> 6;
    const int lane = t & 63;
    const int m    = lane & 15;
    const int quad = lane >> 4;
    const int rowBase = blockIdx.x * 128 + w * 32;
    const int swm = (m & 7) << 3;      // row-swizzle term for fragment reads

    // ---- prefetch ALL layer-1 A into bf16 registers (32x16B loads in flight)
    short8 afr[2][8];
#pragma unroll
    for (int rt = 0; rt < 2; ++rt) {
        int row = rowBase + rt * 16 + m;
        row = row < N_NODES ? row : N_NODES - 1;
        const float* xp = X + (size_t)row * 256 + quad * 8;
#pragma unroll
        for (int kk = 0; kk < 8; ++kk) {
            floatx4 a0 = *(const floatx4*)(xp + kk * 32);
            floatx4 a1 = *(const floatx4*)(xp + kk * 32 + 4);
            short8 v;
            v[0] = (short)f2bf(a0[0]); v[1] = (short)f2bf(a0[1]);
            v[2] = (short)f2bf(a0[2]); v[3] = (short)f2bf(a0[3]);
            v[4] = (short)f2bf(a1[0]); v[5] = (short)f2bf(a1[1]);
            v[6] = (short)f2bf(a1[2]); v[7] = (short)f2bf(a1[3]);
            afr[rt][kk] = v;
        }
    }

    floatx4 acc[2][8];
#pragma unroll
    for (int rt = 0; rt < 2; ++rt)
#pragma unroll
        for (int ct = 0; ct < 8; ++ct) acc[rt][ct] = (floatx4)0.f;

    // ================= Layer 1: x(256) -> h1(128) =================
    // FULLY UNROLLED k-block loop: afr indices stay compile-time constant.
#pragma unroll
    for (int kb4 = 0; kb4 < 4; ++kb4) {
        // stage W1[:, kb4*64 .. +64) as bf16, swizzled
#pragma unroll
        for (int j = 0; j < 8; ++j) {
            int flat = j * 256 + t;
            int n  = flat >> 4;
            int c4 = (flat & 15) * 4;
            floatx4 v = *(const floatx4*)&W1[(size_t)n * 256 + kb4 * 64 + c4];
            *(uint2*)&Wl[n * 64 + (c4 ^ ((n & 7) << 3))] =
                make_uint2(pk2(v[0], v[1]), pk2(v[2], v[3]));
        }
        __syncthreads();
#pragma unroll
        for (int ks = 0; ks < 2; ++ks) {
#pragma unroll
            for (int ct = 0; ct < 8; ++ct) {
                short8 bf = *(const short8*)
                    &Wl[(ct * 16 + m) * 64 + ((ks * 32 + quad * 8) ^ swm)];
                acc[0][ct] = __builtin_amdgcn_mfma_f32_16x16x32_bf16(
                    afr[0][kb4 * 2 + ks], bf, acc[0][ct], 0, 0, 0);
                acc[1][ct] = __builtin_amdgcn_mfma_f32_16x16x32_bf16(
                    afr[1][kb4 * 2 + ks], bf, acc[1][ct], 0, 0, 0);
            }
        }
        __syncthreads();
    }

    // h1 = relu(acc + b1) -> Hb (bf16, swizzled). Each wave owns its 32 rows.
    {
        float br[8];
#pragma unroll
        for (int ct = 0; ct < 8; ++ct) br[ct] = B1[ct * 16 + m];
#pragma unroll
        for (int rt = 0; rt < 2; ++rt)
#pragma unroll
            for (int r = 0; r < 4; ++r) {
                int lrow = w * 32 + rt * 16 + quad * 4 + r;
                int sw = (lrow & 7) << 3;
#pragma unroll
                for (int ct = 0; ct < 8; ++ct) {
                    float v = acc[rt][ct][r] + br[ct];
                    v = v > 0.f ? v : 0.f;
                    Hb[lrow * 128 + ((ct * 16 + m) ^ sw)] = f2bf(v);
                }
            }
    }

#pragma unroll
    for (int rt = 0; rt < 2; ++rt)
#pragma unroll
        for (int ct = 0; ct < 8; ++ct) acc[rt][ct] = (floatx4)0.f;

    // ================= Layer 2: h1(128) -> h2(128) =================
#pragma unroll
    for (int kb2 = 0; kb2 < 2; ++kb2) {
#pragma unroll
        for (int j = 0; j < 8; ++j) {
            int flat = j * 256 + t;
            int n  = flat >> 4;
            int c4 = (flat & 15) * 4;
            floatx4 v = *(const floatx4*)&W2[(size_t)n * 128 + kb2 * 64 + c4];
            *(uint2*)&Wl[n * 64 + (c4 ^ ((n & 7) << 3))] =
                make_uint2(pk2(v[0], v[1]), pk2(v[2], v[3]));
        }
        __syncthreads();   // also makes this wave's Hb writes safely ordered
#pragma unroll
        for (int ks = 0; ks < 2; ++ks) {
            short8 af[2];
#pragma unroll
            for (int rt = 0; rt < 2; ++rt) {
                int lrow = w * 32 + rt * 16 + m;
                int col  = kb2 * 64 + ks * 32 + quad * 8;
                af[rt] = *(const short8*)&Hb[lrow * 128 + (col ^ swm)];
            }
#pragma unroll
            for (int ct = 0; ct < 8; ++ct) {
                short8 bf = *(const short8*)
                    &Wl[(ct * 16 + m) * 64 + ((ks * 32 + quad * 8) ^ swm)];
                acc[0][ct] = __builtin_amdgcn_mfma_f32_16x16x32_bf16(
                    af[0], bf, acc[0][ct], 0, 0, 0);
                acc[1][ct] = __builtin_amdgcn_mfma_f32_16x16x32_bf16(
                    af[1], bf, acc[1][ct], 0, 0, 0);
            }
        }
        __syncthreads();
    }

    // h2 = relu(acc + b2) -> Hb (overwrite own rows; reads drained by barrier)
    {
        float br[8];
#pragma unroll
        for (int ct = 0; ct < 8; ++ct) br[ct] = B2[ct * 16 + m];
#pragma unroll
        for (int rt = 0; rt < 2; ++rt)
#pragma unroll
            for (int r = 0; r < 4; ++r) {
                int lrow = w * 32 + rt * 16 + quad * 4 + r;
                int sw = (lrow & 7) << 3;
#pragma unroll
                for (int ct = 0; ct < 8; ++ct) {
                    float v = acc[rt][ct][r] + br[ct];
                    v = v > 0.f ? v : 0.f;
                    Hb[lrow * 128 + ((ct * 16 + m) ^ sw)] = f2bf(v);
                }
            }
    }

    // ================= Layer 3: h2(128) -> h3(16) =================
    // stage all of W3 (16 x 128) bf16, swizzled
#pragma unroll
    for (int j = 0; j < 2; ++j) {
        int flat = j * 256 + t;
        int n  = flat >> 5;          // 0..15
        int c4 = (flat & 31) * 4;    // 0..124
        floatx4 v = *(const floatx4*)&W3[(size_t)n * 128 + c4];
        *(uint2*)&Wl[n * 128 + (c4 ^ ((n & 7) << 3))] =
            make_uint2(pk2(v[0], v[1]), pk2(v[2], v[3]));
    }
    __syncthreads();

    floatx4 acc3[2];
    acc3[0] = (floatx4)0.f; acc3[1] = (floatx4)0.f;
#pragma unroll
    for (int ks4 = 0; ks4 < 4; ++ks4) {
        int col = ks4 * 32 + quad * 8;
        short8 bf = *(const short8*)&Wl[m * 128 + (col ^ swm)];
#pragma unroll
        for (int rt = 0; rt < 2; ++rt) {
            int lrow = w * 32 + rt * 16 + m;
            short8 af = *(const short8*)&Hb[lrow * 128 + (col ^ swm)];
            acc3[rt] = __builtin_amdgcn_mfma_f32_16x16x32_bf16(
                af, bf, acc3[rt], 0, 0, 0);
        }
    }

    // ---- epilogue: h3 = relu(acc3+b3) -> hops[0] (scoring in combine_all)
    const float b3m = B3[m];
#pragma unroll
    for (int rt = 0; rt < 2; ++rt)
#pragma unroll
        for (int r = 0; r < 4; ++r) {
            int row = rowBase + rt * 16 + quad * 4 + r;
            float v = acc3[rt][r] + b3m;
            v = v > 0.f ? v : 0.f;
            if (row < N_NODES) H0[(size_t)row * 16 + m] = f2bf(v);
        }
}

// ---------------------------------------------------------------------------
// CSR stage 1: per-chunk per-partition histogram -> cmat[p*NCHUNK + chunk]
// ---------------------------------------------------------------------------
__global__ __launch_bounds__(256) void hist2(
    const int* __restrict__ dst, int* __restrict__ cmat)
{
    __shared__ int lhist[NPART];
    const int t = threadIdx.x;
    for (int p = t; p < NPART; p += 256) lhist[p] = 0;
    __syncthreads();
    const int base = blockIdx.x * CHUNK;
#pragma unroll
    for (int j = 0; j < EPT; ++j) {
        int i = base + j * 256 + t;
        if (i < E_EDGES) atomicAdd(&lhist[dst[i] >> 8], 1);
    }
    __syncthreads();
    for (int p = t; p < NPART; p += 256)
        cmat[p * NCHUNK + blockIdx.x] = lhist[p];
}

// ---------------------------------------------------------------------------
// Scan level A: per-8192-segment reduction -> bsum
// ---------------------------------------------------------------------------
__global__ __launch_bounds__(1024) void scan_reduce(
    const int* __restrict__ cmat, int* __restrict__ bsum)
{
    __shared__ int wsum[16];
    const int t = threadIdx.x, lane = t & 63, wid = t >> 6;
    int base = blockIdx.x * SSEG + t * 8;
    int s = 0;
#pragma unroll
    for (int j = 0; j < 8; ++j) {
        int idx = base + j;
        if (idx < NFLAT) s += cmat[idx];
    }
#pragma unroll
    for (int d = 1; d < 64; d <<= 1) s += __shfl_xor(s, d);
    if (lane == 0) wsum[wid] = s;
    __syncthreads();
    if (t == 0) {
        int tot = 0;
#pragma unroll
        for (int i = 0; i < 16; ++i) tot += wsum[i];
        bsum[blockIdx.x] = tot;
    }
}

// ---------------------------------------------------------------------------
// Scan level B: exclusive scan of GA block sums (single wave)
// ---------------------------------------------------------------------------
__global__ void scan_tops(const int* __restrict__ bsum, int* __restrict__ boff)
{
    const int t = threadIdx.x;
    int v = (t < GA) ? bsum[t] : 0;
    int x = v;
#pragma unroll
    for (int d = 1; d < 64; d <<= 1) {
        int y = __shfl_up(x, d);
        if (t >= d) x += y;
    }
    if (t < GA) boff[t] = x - v;
}

// ---------------------------------------------------------------------------
// Scan level C: full exclusive scan applied in-place; also emits pbase[].
// ---------------------------------------------------------------------------
__global__ __launch_bounds__(1024) void scan_apply(
    int* __restrict__ cmat, const int* __restrict__ boff, int* __restrict__ pbase)
{
    __shared__ int wsum[16];
    __shared__ int woff[17];
    const int t = threadIdx.x, lane = t & 63, wid = t >> 6;
    int base = blockIdx.x * SSEG + t * 8;
    int v[8], pre[8];
    int s = 0;
#pragma unroll
    for (int j = 0; j < 8; ++j) {
        int idx = base + j;
        v[j] = (idx < NFLAT) ? cmat[idx] : 0;
        pre[j] = s;
        s += v[j];
    }
    int x = s;
#pragma unroll
    for (int d = 1; d < 64; d <<= 1) {
        int y = __shfl_up(x, d);
        if (lane >= d) x += y;
    }
    if (lane == 63) wsum[wid] = x;
    __syncthreads();
    if (wid == 0) {
        int w = (lane < 16) ? wsum[lane] : 0;
#pragma unroll
        for (int d = 1; d < 16; d <<= 1) {
            int y = __shfl_up(w, d);
            if (lane >= d) w += y;
        }
        if (lane < 16) woff[lane + 1] = w;
        if (lane == 0) woff[0] = 0;
    }
    __syncthreads();
    int tbase = boff[blockIdx.x] + woff[wid] + (x - s);
#pragma unroll
    for (int j = 0; j < 8; ++j) {
        int idx = base + j;
        if (idx < NFLAT) {
            int e = tbase + pre[j];
            cmat[idx] = e;
            if (idx % NCHUNK == 0) pbase[idx / NCHUNK] = e;
        }
    }
    if (blockIdx.x == 0 && t == 0) pbase[NPART] = E_EDGES;
}

// ---------------------------------------------------------------------------
// CSR stage 2: LDS-sorted scatter.
// ---------------------------------------------------------------------------
__global__ __launch_bounds__(256) void scatter3(
    const int* __restrict__ src, const int* __restrict__ dst,
    const float* __restrict__ ea, const int* __restrict__ cbase,
    int2* __restrict__ staging)
{
    __shared__ int2 ebuf[CHUNK];     // 32 KB sorted entries
    __shared__ int  gaddr[CHUNK];    // 16 KB global positions
    __shared__ int  lcnt[NPART];     // counts -> cursors (local sorted idx)
    __shared__ int  goff[NPART];     // global pos = goff[p] + local idx
    __shared__ int  wsum[4];
    const int t = threadIdx.x;
    const int b = blockIdx.x;
    const int base = b * CHUNK;
    const int cnt = min(CHUNK, E_EDGES - base);
    const int lane = t & 63, wid = t >> 6;

    for (int p = t; p < NPART; p += 256) lcnt[p] = 0;
    __syncthreads();

    int d[EPT];
#pragma unroll
    for (int j = 0; j < EPT; ++j) {
        int i = base + j * 256 + t;
        d[j] = (i < E_EDGES) ? dst[i] : -1;
        if (d[j] >= 0) atomicAdd(&lcnt[d[j] >> 8], 1);
    }
    __syncthreads();

    int v0 = (2 * t     < NPART) ? lcnt[2 * t]     : 0;
    int v1 = (2 * t + 1 < NPART) ? lcnt[2 * t + 1] : 0;
    int pair = v0 + v1;
    int x = pair;
#pragma unroll
    for (int dd = 1; dd < 64; dd <<= 1) {
        int y = __shfl_up(x, dd);
        if (lane >= dd) x += y;
    }
    if (lane == 63) wsum[wid] = x;
    __syncthreads();
    int wbase = 0;
#pragma unroll
    for (int w = 0; w < 4; ++w) if (w < wid) wbase += wsum[w];
    int excl = wbase + x - pair;
    if (2 * t < NPART) {
        lcnt[2 * t] = excl;
        goff[2 * t] = cbase[(2 * t) * NCHUNK + b] - excl;
    }
    if (2 * t + 1 < NPART) {
        lcnt[2 * t + 1] = excl + v0;
        goff[2 * t + 1] = cbase[(2 * t + 1) * NCHUNK + b] - (excl + v0);
    }
    __syncthreads();

#pragma unroll
    for (int j = 0; j < EPT; ++j) {
        if (d[j] >= 0) {
            int i = base + j * 256 + t;
            int p = d[j] >> 8;
            int s = atomicAdd(&lcnt[p], 1);
            ebuf[s]  = make_int2(__float_as_int(ea[i]),
                                 src[i] | ((d[j] & 255) << 17));
            gaddr[s] = goff[p] + s;
        }
    }
    __syncthreads();

    for (int k = t; k < cnt; k += 256)
        staging[gaddr[k]] = ebuf[k];
}

// ---------------------------------------------------------------------------
// CSR stage 3: one 1024-thread block per partition -> rowp + final CSR.
// ---------------------------------------------------------------------------
__global__ __launch_bounds__(1024) void partition_build(
    const int2* __restrict__ staging, const int* __restrict__ pbase,
    int* __restrict__ rowp, int2* __restrict__ csr)
{
    __shared__ int ncnt[NPP];
    __shared__ int wsum[4];
    const int p = blockIdx.x;
    const int t = threadIdx.x;
    const int e0 = pbase[p], e1 = pbase[p + 1];
    const int cnt = e1 - e0;
    const int n0 = p << 8;

    if (t < NPP) ncnt[t] = 0;
    __syncthreads();
    for (int e = t; e < cnt; e += 1024)
        atomicAdd(&ncnt[(staging[e0 + e].y >> 17) & 255], 1);
    __syncthreads();

    int x = 0, v = 0;
    if (t < NPP) {
        const int lane = t & 63, wid = t >> 6;
        v = ncnt[t];
        x = v;
#pragma unroll
        for (int d = 1; d < 64; d <<= 1) {
            int y = __shfl_up(x, d);
            if (lane >= d) x += y;
        }
        if (lane == 63) wsum[wid] = x;
    }
    __syncthreads();
    if (t < NPP) {
        const int wid = t >> 6;
        int wbase = 0;
#pragma unroll
        for (int w = 0; w < 4; ++w) if (w < wid) wbase += wsum[w];
        int excl = wbase + x - v;
        ncnt[t] = e0 + excl;
        int n = n0 + t;
        if (n < N_NODES) rowp[n] = e0 + excl;
    }
    if (p == NPART - 1 && t == 0) rowp[N_NODES] = E_EDGES;
    __syncthreads();

    for (int e = t; e < cnt; e += 1024) {
        int2 en = staging[e0 + e];
        int dlo = (en.y >> 17) & 255;
        int pos = atomicAdd(&ncnt[dlo], 1);
        csr[pos] = make_int2(en.y & 0x1FFFF, en.x);
    }
}

// ---------------------------------------------------------------------------
// One hop (bf16 states), gather only. 8 lanes/node, 4 gathers in flight.
// csr/rowp are read via NON-TEMPORAL loads (as scalar int64 -- the builtin
// rejects HIP vector types): the 25.6MB csr stream otherwise cycles through
// the 4MB per-XCD L2 every hop and evicts the 3.2MB prev table, turning the
// random gathers into L3 misses. With nt csr, prev stays L2-resident (fits
// 8x over) and gathers are L2 hits.
// ---------------------------------------------------------------------------
__global__ __launch_bounds__(256) void hop_bf16(
    const ushort* __restrict__ prev, ushort* __restrict__ next,
    const int* __restrict__ rowp, const int2* __restrict__ csr)
{
    const int t = threadIdx.x;
    const int l = t & 1;
    const int g = (t >> 1) & 3;
    const int n = blockIdx.x * 32 + (t >> 3);
    if (n >= N_NODES) return;
    const int e0 = __builtin_nontemporal_load(rowp + n);
    const int e1 = __builtin_nontemporal_load(rowp + n + 1);
    const long long* csrq = (const long long*)csr;
    float a[8];
#pragma unroll
    for (int j = 0; j < 8; ++j) a[j] = 0.f;

    int e = e0 + g;
    for (; e + 12 < e1; e += 16) {
        long long q0 = __builtin_nontemporal_load(csrq + e);
        long long q1 = __builtin_nontemporal_load(csrq + e + 4);
        long long q2 = __builtin_nontemporal_load(csrq + e + 8);
        long long q3 = __builtin_nontemporal_load(csrq + e + 12);
        int s0 = (int)(q0 & 0x1FFFF), s1 = (int)(q1 & 0x1FFFF);
        int s2 = (int)(q2 & 0x1FFFF), s3 = (int)(q3 & 0x1FFFF);
        float w0 = __uint_as_float((uint)(q0 >> 32));
        float w1 = __uint_as_float((uint)(q1 >> 32));
        float w2 = __uint_as_float((uint)(q2 >> 32));
        float w3 = __uint_as_float((uint)(q3 >> 32));
        uint4 v0 = *(const uint4*)&prev[(size_t)s0 * 16 + l * 8];
        uint4 v1 = *(const uint4*)&prev[(size_t)s1 * 16 + l * 8];
        uint4 v2 = *(const uint4*)&prev[(size_t)s2 * 16 + l * 8];
        uint4 v3 = *(const uint4*)&prev[(size_t)s3 * 16 + l * 8];
        a[0] += w0 * bflo(v0.x); a[1] += w0 * bfhi(v0.x);
        a[2] += w0 * bflo(v0.y); a[3] += w0 * bfhi(v0.y);
        a[4] += w0 * bflo(v0.z); a[5] += w0 * bfhi(v0.z);
        a[6] += w0 * bflo(v0.w); a[7] += w0 * bfhi(v0.w);
        a[0] += w1 * bflo(v1.x); a[1] += w1 * bfhi(v1.x);
        a[2] += w1 * bflo(v1.y); a[3] += w1 * bfhi(v1.y);
        a[4] += w1 * bflo(v1.z); a[5] += w1 * bfhi(v1.z);
        a[6] += w1 * bflo(v1.w); a[7] += w1 * bfhi(v1.w);
        a[0] += w2 * bflo(v2.x); a[1] += w2 * bfhi(v2.x);
        a[2] += w2 * bflo(v2.y); a[3] += w2 * bfhi(v2.y);
        a[4] += w2 * bflo(v2.z); a[5] += w2 * bfhi(v2.z);
        a[6] += w2 * bflo(v2.w); a[7] += w2 * bfhi(v2.w);
        a[0] += w3 * bflo(v3.x); a[1] += w3 * bfhi(v3.x);
        a[2] += w3 * bflo(v3.y); a[3] += w3 * bfhi(v3.y);
        a[4] += w3 * bflo(v3.z); a[5] += w3 * bfhi(v3.z);
        a[6] += w3 * bflo(v3.w); a[7] += w3 * bfhi(v3.w);
    }
    for (; e < e1; e += 4) {
        long long q0 = __builtin_nontemporal_load(csrq + e);
        int s0 = (int)(q0 & 0x1FFFF);
        float w0 = __uint_as_float((uint)(q0 >> 32));
        uint4 v0 = *(const uint4*)&prev[(size_t)s0 * 16 + l * 8];
        a[0] += w0 * bflo(v0.x); a[1] += w0 * bfhi(v0.x);
        a[2] += w0 * bflo(v0.y); a[3] += w0 * bfhi(v0.y);
        a[4] += w0 * bflo(v0.z); a[5] += w0 * bfhi(v0.z);
        a[6] += w0 * bflo(v0.w); a[7] += w0 * bfhi(v0.w);
    }

#pragma unroll
    for (int d = 2; d <= 4; d <<= 1) {
#pragma unroll
        for (int j = 0; j < 8; ++j) a[j] += __shfl_xor(a[j], d);
    }

    if (g == 0) {
        uint4 nv = make_uint4(pk2(a[0], a[1]), pk2(a[2], a[3]),
                              pk2(a[4], a[5]), pk2(a[6], a[7]));
        *(uint4*)&next[(size_t)n * 16 + l * 8] = nv;
    }
}

// ---------------------------------------------------------------------------
// Final combine: out[n] = sum_k sigmoid(hops[k][n].pw + pb) * hops[k][n].
// 2 lanes/node, 11 independent 16B loads in flight per lane.
// ---------------------------------------------------------------------------
__global__ __launch_bounds__(256) void combine_all(
    const ushort* __restrict__ hops,   // (K+1) buffers, stride N*16
    const float* __restrict__ pw, const float* __restrict__ pb,
    float* __restrict__ out)
{
    const int t = threadIdx.x;
    const int l = t & 1;
    const int n = blockIdx.x * 128 + (t >> 1);
    if (n >= N_NODES) return;
    float4 p0 = ((const float4*)pw)[l * 2];
    float4 p1 = ((const float4*)pw)[l * 2 + 1];
    const float pb0 = pb[0];
    float o0 = 0.f, o1 = 0.f, o2 = 0.f, o3 = 0.f;
    float o4 = 0.f, o5 = 0.f, o6 = 0.f, o7 = 0.f;
#pragma unroll
    for (int k = 0; k <= K_HOPS; ++k) {
        uint4 v = *(const uint4*)
            &hops[((size_t)k * N_NODES + n) * 16 + l * 8];
        float a0 = bflo(v.x), a1 = bfhi(v.x), a2 = bflo(v.y), a3 = bfhi(v.y);
        float a4 = bflo(v.z), a5 = bfhi(v.z), a6 = bflo(v.w), a7 = bfhi(v.w);
        float part = a0*p0.x + a1*p0.y + a2*p0.z + a3*p0.w
                   + a4*p1.x + a5*p1.y + a6*p1.z + a7*p1.w;
        part += __shfl_xor(part, 1);
        float s = 1.f / (1.f + __expf(-(part + pb0)));
        o0 += s*a0; o1 += s*a1; o2 += s*a2; o3 += s*a3;
        o4 += s*a4; o5 += s*a5; o6 += s*a6; o7 += s*a7;
    }
    *(float4*)&out[(size_t)n * 16 + l * 8]     = make_float4(o0, o1, o2, o3);
    *(float4*)&out[(size_t)n * 16 + l * 8 + 4] = make_float4(o4, o5, o6, o7);
}

// ---------------------------------------------------------------------------
extern "C" void kernel_launch(void* const* d_in, const int* in_sizes, int n_in,
                              void* d_out, int out_size, void* d_ws, size_t ws_size,
                              hipStream_t stream)
{
    const float* x  = (const float*)d_in[0];
    const int*   ei = (const int*)d_in[1];
    const float* ea = (const float*)d_in[2];
    const float* w1 = (const float*)d_in[3];
    const float* b1 = (const float*)d_in[4];
    const float* w2 = (const float*)d_in[5];
    const float* b2 = (const float*)d_in[6];
    const float* w3 = (const float*)d_in[7];
    const float* b3 = (const float*)d_in[8];
    const float* pw = (const float*)d_in[9];
    const float* pb = (const float*)d_in[10];
    float* out = (float*)d_out;

    char* ws = (char*)d_ws;
    size_t off = 0;
    char*   region0 = ws + off;           off += (size_t)E_EDGES * 16;       // 51.2 MB
    int*    rowp  = (int*)(ws + off);     off += (((size_t)(N_NODES + 1) * 4) + 15) & ~(size_t)15;
    int*    cmat  = (int*)(ws + off);     off += ((size_t)NFLAT * 4 + 15) & ~(size_t)15;  // 1.22 MB
    int*    bsum  = (int*)(ws + off);     off += ((size_t)GA * 4 + 15) & ~(size_t)15;
    int*    boff  = (int*)(ws + off);     off += ((size_t)GA * 4 + 15) & ~(size_t)15;
    int*    pbase = (int*)(ws + off);     off += ((size_t)(NPART + 1) * 4 + 15) & ~(size_t)15;
    int2*   csr   = (int2*)(ws + off);    off += (size_t)E_EDGES * 8;        // 25.6 MB

    // staging (25.6MB) lives in region0 during CSR build; afterwards region0
    // holds the 11 hop-state buffers (11 x 3.2MB = 35.2MB <= 51.2MB).
    // Stream-ordered: partition_build finishes staging reads before
    // fused_mlp writes hops[0].
    int2*   staging = (int2*)region0;
    ushort* hops    = (ushort*)region0;
    const size_t HSTRIDE = (size_t)N_NODES * 16;   // ushorts per hop buffer

    const int* src = ei;
    const int* dst = ei + E_EDGES;

    const dim3 blk(256);
    const int mlpGrid    = (N_NODES + 127) / 128;   // 782
    const int hopGrid    = (N_NODES + 31) / 32;     // 3125

    // ---- CSR build: contention-free multi-split ----
    hist2<<<NCHUNK, blk, 0, stream>>>(dst, cmat);
    scan_reduce<<<GA, 1024, 0, stream>>>(cmat, bsum);
    scan_tops<<<1, 64, 0, stream>>>(bsum, boff);
    scan_apply<<<GA, 1024, 0, stream>>>(cmat, boff, pbase);
    scatter3<<<NCHUNK, blk, 0, stream>>>(src, dst, ea, cmat, staging);
    partition_build<<<NPART, 1024, 0, stream>>>(staging, pbase, rowp, csr);

    // ---- fused MLP (3 layers) -> hops[0] ----
    fused_mlp<<<mlpGrid, blk, 0, stream>>>(x, w1, b1, w2, b2, w3, b3, hops);

    // ---- K hops (gather only, nt csr stream) ----
    for (int k = 0; k < K_HOPS; ++k) {
        hop_bf16<<<hopGrid, blk, 0, stream>>>(hops + (size_t)k * HSTRIDE,
                                              hops + (size_t)(k + 1) * HSTRIDE,
                                              rowp, csr);
    }

    // ---- final combine over all K+1 states ----
    combine_all<<<mlpGrid, blk, 0, stream>>>(hops, pw, pb, out);
}

// Round 11
// 652.463 us; speedup vs baseline: 1.0271x; 1.0271x over previous
//
#include <hip/hip_runtime.h>
#include <hip/hip_bf16.h>
#include <math.h>

#define N_NODES 100000
#define E_EDGES 3200000
#define K_HOPS  10
#define NPP     256                          // nodes per partition (dst>>8)
#define NPART   ((N_NODES + NPP - 1) / NPP)  // 391 partitions
#define CHUNK   4096                         // edges per scatter block
#define EPT     (CHUNK / 256)                // 16 edges per thread
#define NCHUNK  ((E_EDGES + CHUNK - 1) / CHUNK)   // 782 chunks
#define NFLAT   (NPART * NCHUNK)                  // 305762
#define SSEG    8192
#define GA      ((NFLAT + SSEG - 1) / SSEG)       // 38 scan blocks

typedef __attribute__((ext_vector_type(8))) short short8;
typedef __attribute__((ext_vector_type(4))) float floatx4;

__device__ __forceinline__ ushort f2bf(float f) {
    uint u = __float_as_uint(f);
    u += 0x7fffu + ((u >> 16) & 1u);
    return (ushort)(u >> 16);
}
__device__ __forceinline__ uint pk2(float a, float b) {
    return (uint)f2bf(a) | ((uint)f2bf(b) << 16);
}
__device__ __forceinline__ float bflo(uint u) { return __uint_as_float(u << 16); }
__device__ __forceinline__ float bfhi(uint u) { return __uint_as_float(u & 0xffff0000u); }

// ---------------------------------------------------------------------------
// Fused 3-layer MLP (256->128->128->16, relu). Writes bf16 h3 -> hops[0].
// One block = 128 rows, 4 waves x 32 rows. h1/h2 never leave LDS.
// Layer-1 A prefetched into 64 bf16 VGPRs; (256,2) launch bounds REQUIRED:
// (256,3)'s ~168-VGPR cap (r1/r2) and (256,4)'s 128 cap (r7) both spilled
// the prefetch to scratch (+11..51MB WRITE_SIZE, dur 90-121us). This
// 128-row/(256,2) version is the verified optimum: 64us, VGPR=124,
// WRITE_SIZE ideal. DO NOT re-tune occupancy here.
// LDS tiles XOR-swizzled: col ^= (row&7)<<3 (ushort units, 16B groups).
// ---------------------------------------------------------------------------
__global__ __launch_bounds__(256, 2) void fused_mlp(
    const float* __restrict__ X,
    const float* __restrict__ W1, const float* __restrict__ B1,
    const float* __restrict__ W2, const float* __restrict__ B2,
    const float* __restrict__ W3, const float* __restrict__ B3,
    ushort* __restrict__ H0)      // hops[0]: N x 16 bf16
{
    __shared__ ushort Wl[128 * 64];    // 16 KB: W slice (128 rows x 64 cols bf16)
    __shared__ ushort Hb[128 * 128];   // 32 KB: h tile  (128 rows x 128 cols bf16)

    const int t    = threadIdx.x;
    const int w    = t >> 6;
    const int lane = t & 63;
    const int m    = lane & 15;
    const int quad = lane >> 4;
    const int rowBase = blockIdx.x * 128 + w * 32;
    const int swm = (m & 7) << 3;      // row-swizzle term for fragment reads

    // ---- prefetch ALL layer-1 A into bf16 registers (32x16B loads in flight)
    short8 afr[2][8];
#pragma unroll
    for (int rt = 0; rt < 2; ++rt) {
        int row = rowBase + rt * 16 + m;
        row = row < N_NODES ? row : N_NODES - 1;
        const float* xp = X + (size_t)row * 256 + quad * 8;
#pragma unroll
        for (int kk = 0; kk < 8; ++kk) {
            floatx4 a0 = *(const floatx4*)(xp + kk * 32);
            floatx4 a1 = *(const floatx4*)(xp + kk * 32 + 4);
            short8 v;
            v[0] = (short)f2bf(a0[0]); v[1] = (short)f2bf(a0[1]);
            v[2] = (short)f2bf(a0[2]); v[3] = (short)f2bf(a0[3]);
            v[4] = (short)f2bf(a1[0]); v[5] = (short)f2bf(a1[1]);
            v[6] = (short)f2bf(a1[2]); v[7] = (short)f2bf(a1[3]);
            afr[rt][kk] = v;
        }
    }

    floatx4 acc[2][8];
#pragma unroll
    for (int rt = 0; rt < 2; ++rt)
#pragma unroll
        for (int ct = 0; ct < 8; ++ct) acc[rt][ct] = (floatx4)0.f;

    // ================= Layer 1: x(256) -> h1(128) =================
    // FULLY UNROLLED k-block loop: afr indices stay compile-time constant.
#pragma unroll
    for (int kb4 = 0; kb4 < 4; ++kb4) {
        // stage W1[:, kb4*64 .. +64) as bf16, swizzled
#pragma unroll
        for (int j = 0; j < 8; ++j) {
            int flat = j * 256 + t;
            int n  = flat >> 4;
            int c4 = (flat & 15) * 4;
            floatx4 v = *(const floatx4*)&W1[(size_t)n * 256 + kb4 * 64 + c4];
            *(uint2*)&Wl[n * 64 + (c4 ^ ((n & 7) << 3))] =
                make_uint2(pk2(v[0], v[1]), pk2(v[2], v[3]));
        }
        __syncthreads();
#pragma unroll
        for (int ks = 0; ks < 2; ++ks) {
#pragma unroll
            for (int ct = 0; ct < 8; ++ct) {
                short8 bf = *(const short8*)
                    &Wl[(ct * 16 + m) * 64 + ((ks * 32 + quad * 8) ^ swm)];
                acc[0][ct] = __builtin_amdgcn_mfma_f32_16x16x32_bf16(
                    afr[0][kb4 * 2 + ks], bf, acc[0][ct], 0, 0, 0);
                acc[1][ct] = __builtin_amdgcn_mfma_f32_16x16x32_bf16(
                    afr[1][kb4 * 2 + ks], bf, acc[1][ct], 0, 0, 0);
            }
        }
        __syncthreads();
    }

    // h1 = relu(acc + b1) -> Hb (bf16, swizzled). Each wave owns its 32 rows.
    {
        float br[8];
#pragma unroll
        for (int ct = 0; ct < 8; ++ct) br[ct] = B1[ct * 16 + m];
#pragma unroll
        for (int rt = 0; rt < 2; ++rt)
#pragma unroll
            for (int r = 0; r < 4; ++r) {
                int lrow = w * 32 + rt * 16 + quad * 4 + r;
                int sw = (lrow & 7) << 3;
#pragma unroll
                for (int ct = 0; ct < 8; ++ct) {
                    float v = acc[rt][ct][r] + br[ct];
                    v = v > 0.f ? v : 0.f;
                    Hb[lrow * 128 + ((ct * 16 + m) ^ sw)] = f2bf(v);
                }
            }
    }

#pragma unroll
    for (int rt = 0; rt < 2; ++rt)
#pragma unroll
        for (int ct = 0; ct < 8; ++ct) acc[rt][ct] = (floatx4)0.f;

    // ================= Layer 2: h1(128) -> h2(128) =================
#pragma unroll
    for (int kb2 = 0; kb2 < 2; ++kb2) {
#pragma unroll
        for (int j = 0; j < 8; ++j) {
            int flat = j * 256 + t;
            int n  = flat >> 4;
            int c4 = (flat & 15) * 4;
            floatx4 v = *(const floatx4*)&W2[(size_t)n * 128 + kb2 * 64 + c4];
            *(uint2*)&Wl[n * 64 + (c4 ^ ((n & 7) << 3))] =
                make_uint2(pk2(v[0], v[1]), pk2(v[2], v[3]));
        }
        __syncthreads();   // also makes this wave's Hb writes safely ordered
#pragma unroll
        for (int ks = 0; ks < 2; ++ks) {
            short8 af[2];
#pragma unroll
            for (int rt = 0; rt < 2; ++rt) {
                int lrow = w * 32 + rt * 16 + m;
                int col  = kb2 * 64 + ks * 32 + quad * 8;
                af[rt] = *(const short8*)&Hb[lrow * 128 + (col ^ swm)];
            }
#pragma unroll
            for (int ct = 0; ct < 8; ++ct) {
                short8 bf = *(const short8*)
                    &Wl[(ct * 16 + m) * 64 + ((ks * 32 + quad * 8) ^ swm)];
                acc[0][ct] = __builtin_amdgcn_mfma_f32_16x16x32_bf16(
                    af[0], bf, acc[0][ct], 0, 0, 0);
                acc[1][ct] = __builtin_amdgcn_mfma_f32_16x16x32_bf16(
                    af[1], bf, acc[1][ct], 0, 0, 0);
            }
        }
        __syncthreads();
    }

    // h2 = relu(acc + b2) -> Hb (overwrite own rows; reads drained by barrier)
    {
        float br[8];
#pragma unroll
        for (int ct = 0; ct < 8; ++ct) br[ct] = B2[ct * 16 + m];
#pragma unroll
        for (int rt = 0; rt < 2; ++rt)
#pragma unroll
            for (int r = 0; r < 4; ++r) {
                int lrow = w * 32 + rt * 16 + quad * 4 + r;
                int sw = (lrow & 7) << 3;
#pragma unroll
                for (int ct = 0; ct < 8; ++ct) {
                    float v = acc[rt][ct][r] + br[ct];
                    v = v > 0.f ? v : 0.f;
                    Hb[lrow * 128 + ((ct * 16 + m) ^ sw)] = f2bf(v);
                }
            }
    }

    // ================= Layer 3: h2(128) -> h3(16) =================
    // stage all of W3 (16 x 128) bf16, swizzled
#pragma unroll
    for (int j = 0; j < 2; ++j) {
        int flat = j * 256 + t;
        int n  = flat >> 5;          // 0..15
        int c4 = (flat & 31) * 4;    // 0..124
        floatx4 v = *(const floatx4*)&W3[(size_t)n * 128 + c4];
        *(uint2*)&Wl[n * 128 + (c4 ^ ((n & 7) << 3))] =
            make_uint2(pk2(v[0], v[1]), pk2(v[2], v[3]));
    }
    __syncthreads();

    floatx4 acc3[2];
    acc3[0] = (floatx4)0.f; acc3[1] = (floatx4)0.f;
#pragma unroll
    for (int ks4 = 0; ks4 < 4; ++ks4) {
        int col = ks4 * 32 + quad * 8;
        short8 bf = *(const short8*)&Wl[m * 128 + (col ^ swm)];
#pragma unroll
        for (int rt = 0; rt < 2; ++rt) {
            int lrow = w * 32 + rt * 16 + m;
            short8 af = *(const short8*)&Hb[lrow * 128 + (col ^ swm)];
            acc3[rt] = __builtin_amdgcn_mfma_f32_16x16x32_bf16(
                af, bf, acc3[rt], 0, 0, 0);
        }
    }

    // ---- epilogue: h3 = relu(acc3+b3) -> hops[0] (scoring in combine_all)
    const float b3m = B3[m];
#pragma unroll
    for (int rt = 0; rt < 2; ++rt)
#pragma unroll
        for (int r = 0; r < 4; ++r) {
            int row = rowBase + rt * 16 + quad * 4 + r;
            float v = acc3[rt][r] + b3m;
            v = v > 0.f ? v : 0.f;
            if (row < N_NODES) H0[(size_t)row * 16 + m] = f2bf(v);
        }
}

// ---------------------------------------------------------------------------
// CSR stage 1: per-chunk per-partition histogram -> cmat[p*NCHUNK + chunk]
// ---------------------------------------------------------------------------
__global__ __launch_bounds__(256) void hist2(
    const int* __restrict__ dst, int* __restrict__ cmat)
{
    __shared__ int lhist[NPART];
    const int t = threadIdx.x;
    for (int p = t; p < NPART; p += 256) lhist[p] = 0;
    __syncthreads();
    const int base = blockIdx.x * CHUNK;
#pragma unroll
    for (int j = 0; j < EPT; ++j) {
        int i = base + j * 256 + t;
        if (i < E_EDGES) atomicAdd(&lhist[dst[i] >> 8], 1);
    }
    __syncthreads();
    for (int p = t; p < NPART; p += 256)
        cmat[p * NCHUNK + blockIdx.x] = lhist[p];
}

// ---------------------------------------------------------------------------
// Scan level A: per-8192-segment reduction -> bsum
// ---------------------------------------------------------------------------
__global__ __launch_bounds__(1024) void scan_reduce(
    const int* __restrict__ cmat, int* __restrict__ bsum)
{
    __shared__ int wsum[16];
    const int t = threadIdx.x, lane = t & 63, wid = t >> 6;
    int base = blockIdx.x * SSEG + t * 8;
    int s = 0;
#pragma unroll
    for (int j = 0; j < 8; ++j) {
        int idx = base + j;
        if (idx < NFLAT) s += cmat[idx];
    }
#pragma unroll
    for (int d = 1; d < 64; d <<= 1) s += __shfl_xor(s, d);
    if (lane == 0) wsum[wid] = s;
    __syncthreads();
    if (t == 0) {
        int tot = 0;
#pragma unroll
        for (int i = 0; i < 16; ++i) tot += wsum[i];
        bsum[blockIdx.x] = tot;
    }
}

// ---------------------------------------------------------------------------
// Scan level B: exclusive scan of GA block sums (single wave)
// ---------------------------------------------------------------------------
__global__ void scan_tops(const int* __restrict__ bsum, int* __restrict__ boff)
{
    const int t = threadIdx.x;
    int v = (t < GA) ? bsum[t] : 0;
    int x = v;
#pragma unroll
    for (int d = 1; d < 64; d <<= 1) {
        int y = __shfl_up(x, d);
        if (t >= d) x += y;
    }
    if (t < GA) boff[t] = x - v;
}

// ---------------------------------------------------------------------------
// Scan level C: full exclusive scan applied in-place; also emits pbase[].
// ---------------------------------------------------------------------------
__global__ __launch_bounds__(1024) void scan_apply(
    int* __restrict__ cmat, const int* __restrict__ boff, int* __restrict__ pbase)
{
    __shared__ int wsum[16];
    __shared__ int woff[17];
    const int t = threadIdx.x, lane = t & 63, wid = t >> 6;
    int base = blockIdx.x * SSEG + t * 8;
    int v[8], pre[8];
    int s = 0;
#pragma unroll
    for (int j = 0; j < 8; ++j) {
        int idx = base + j;
        v[j] = (idx < NFLAT) ? cmat[idx] : 0;
        pre[j] = s;
        s += v[j];
    }
    int x = s;
#pragma unroll
    for (int d = 1; d < 64; d <<= 1) {
        int y = __shfl_up(x, d);
        if (lane >= d) x += y;
    }
    if (lane == 63) wsum[wid] = x;
    __syncthreads();
    if (wid == 0) {
        int w = (lane < 16) ? wsum[lane] : 0;
#pragma unroll
        for (int d = 1; d < 16; d <<= 1) {
            int y = __shfl_up(w, d);
            if (lane >= d) w += y;
        }
        if (lane < 16) woff[lane + 1] = w;
        if (lane == 0) woff[0] = 0;
    }
    __syncthreads();
    int tbase = boff[blockIdx.x] + woff[wid] + (x - s);
#pragma unroll
    for (int j = 0; j < 8; ++j) {
        int idx = base + j;
        if (idx < NFLAT) {
            int e = tbase + pre[j];
            cmat[idx] = e;
            if (idx % NCHUNK == 0) pbase[idx / NCHUNK] = e;
        }
    }
    if (blockIdx.x == 0 && t == 0) pbase[NPART] = E_EDGES;
}

// ---------------------------------------------------------------------------
// CSR stage 2: LDS-sorted scatter.
// ---------------------------------------------------------------------------
__global__ __launch_bounds__(256) void scatter3(
    const int* __restrict__ src, const int* __restrict__ dst,
    const float* __restrict__ ea, const int* __restrict__ cbase,
    int2* __restrict__ staging)
{
    __shared__ int2 ebuf[CHUNK];     // 32 KB sorted entries
    __shared__ int  gaddr[CHUNK];    // 16 KB global positions
    __shared__ int  lcnt[NPART];     // counts -> cursors (local sorted idx)
    __shared__ int  goff[NPART];     // global pos = goff[p] + local idx
    __shared__ int  wsum[4];
    const int t = threadIdx.x;
    const int b = blockIdx.x;
    const int base = b * CHUNK;
    const int cnt = min(CHUNK, E_EDGES - base);
    const int lane = t & 63, wid = t >> 6;

    for (int p = t; p < NPART; p += 256) lcnt[p] = 0;
    __syncthreads();

    int d[EPT];
#pragma unroll
    for (int j = 0; j < EPT; ++j) {
        int i = base + j * 256 + t;
        d[j] = (i < E_EDGES) ? dst[i] : -1;
        if (d[j] >= 0) atomicAdd(&lcnt[d[j] >> 8], 1);
    }
    __syncthreads();

    int v0 = (2 * t     < NPART) ? lcnt[2 * t]     : 0;
    int v1 = (2 * t + 1 < NPART) ? lcnt[2 * t + 1] : 0;
    int pair = v0 + v1;
    int x = pair;
#pragma unroll
    for (int dd = 1; dd < 64; dd <<= 1) {
        int y = __shfl_up(x, dd);
        if (lane >= dd) x += y;
    }
    if (lane == 63) wsum[wid] = x;
    __syncthreads();
    int wbase = 0;
#pragma unroll
    for (int w = 0; w < 4; ++w) if (w < wid) wbase += wsum[w];
    int excl = wbase + x - pair;
    if (2 * t < NPART) {
        lcnt[2 * t] = excl;
        goff[2 * t] = cbase[(2 * t) * NCHUNK + b] - excl;
    }
    if (2 * t + 1 < NPART) {
        lcnt[2 * t + 1] = excl + v0;
        goff[2 * t + 1] = cbase[(2 * t + 1) * NCHUNK + b] - (excl + v0);
    }
    __syncthreads();

#pragma unroll
    for (int j = 0; j < EPT; ++j) {
        if (d[j] >= 0) {
            int i = base + j * 256 + t;
            int p = d[j] >> 8;
            int s = atomicAdd(&lcnt[p], 1);
            ebuf[s]  = make_int2(__float_as_int(ea[i]),
                                 src[i] | ((d[j] & 255) << 17));
            gaddr[s] = goff[p] + s;
        }
    }
    __syncthreads();

    for (int k = t; k < cnt; k += 256)
        staging[gaddr[k]] = ebuf[k];
}

// ---------------------------------------------------------------------------
// CSR stage 3: one 1024-thread block per partition -> rowp + final CSR.
// ---------------------------------------------------------------------------
__global__ __launch_bounds__(1024) void partition_build(
    const int2* __restrict__ staging, const int* __restrict__ pbase,
    int* __restrict__ rowp, int2* __restrict__ csr)
{
    __shared__ int ncnt[NPP];
    __shared__ int wsum[4];
    const int p = blockIdx.x;
    const int t = threadIdx.x;
    const int e0 = pbase[p], e1 = pbase[p + 1];
    const int cnt = e1 - e0;
    const int n0 = p << 8;

    if (t < NPP) ncnt[t] = 0;
    __syncthreads();
    for (int e = t; e < cnt; e += 1024)
        atomicAdd(&ncnt[(staging[e0 + e].y >> 17) & 255], 1);
    __syncthreads();

    int x = 0, v = 0;
    if (t < NPP) {
        const int lane = t & 63, wid = t >> 6;
        v = ncnt[t];
        x = v;
#pragma unroll
        for (int d = 1; d < 64; d <<= 1) {
            int y = __shfl_up(x, d);
            if (lane >= d) x += y;
        }
        if (lane == 63) wsum[wid] = x;
    }
    __syncthreads();
    if (t < NPP) {
        const int wid = t >> 6;
        int wbase = 0;
#pragma unroll
        for (int w = 0; w < 4; ++w) if (w < wid) wbase += wsum[w];
        int excl = wbase + x - v;
        ncnt[t] = e0 + excl;
        int n = n0 + t;
        if (n < N_NODES) rowp[n] = e0 + excl;
    }
    if (p == NPART - 1 && t == 0) rowp[N_NODES] = E_EDGES;
    __syncthreads();

    for (int e = t; e < cnt; e += 1024) {
        int2 en = staging[e0 + e];
        int dlo = (en.y >> 17) & 255;
        int pos = atomicAdd(&ncnt[dlo], 1);
        csr[pos] = make_int2(en.y & 0x1FFFF, en.x);
    }
}

// ---------------------------------------------------------------------------
// One hop (bf16 states), gather only. 8 lanes/node, 4 gathers in flight.
// csr is NON-TEMPORAL (keeps the 25.6MB stream from evicting the 3.2MB prev
// table out of each XCD's 4MB L2) AND SOFTWARE-PREFETCHED one iteration
// ahead (r9 lesson: nt alone put csr's ~900cy HBM latency on the serial
// csr->gather chain, +22%/hop; prefetch takes it off-chain). Gathers should
// now be L2 hits, collapsing the latency x miss-capacity bound (~43us/hop).
// Named pipeline registers (rule #20). rowp: plain loads (tiny).
// ---------------------------------------------------------------------------
__global__ __launch_bounds__(256) void hop_bf16(
    const ushort* __restrict__ prev, ushort* __restrict__ next,
    const int* __restrict__ rowp, const int2* __restrict__ csr)
{
    const int t = threadIdx.x;
    const int l = t & 1;
    const int g = (t >> 1) & 3;
    const int n = blockIdx.x * 32 + (t >> 3);
    if (n >= N_NODES) return;
    const int e0 = rowp[n], e1 = rowp[n + 1];
    const long long* csrq = (const long long*)csr;
    float a[8];
#pragma unroll
    for (int j = 0; j < 8; ++j) a[j] = 0.f;

    int e = e0 + g;
    if (e + 12 < e1) {
        // prologue: csr entries for iteration 0
        long long q0 = __builtin_nontemporal_load(csrq + e);
        long long q1 = __builtin_nontemporal_load(csrq + e + 4);
        long long q2 = __builtin_nontemporal_load(csrq + e + 8);
        long long q3 = __builtin_nontemporal_load(csrq + e + 12);
        for (;;) {
            int en = e + 16;
            bool more = (en + 12 < e1);
            // issue NEXT iteration's csr loads before this iteration's
            // gathers -- csr latency hides under gather+FMA work
            long long p0 = 0, p1 = 0, p2 = 0, p3 = 0;
            if (more) {
                p0 = __builtin_nontemporal_load(csrq + en);
                p1 = __builtin_nontemporal_load(csrq + en + 4);
                p2 = __builtin_nontemporal_load(csrq + en + 8);
                p3 = __builtin_nontemporal_load(csrq + en + 12);
            }
            int s0 = (int)(q0 & 0x1FFFF), s1 = (int)(q1 & 0x1FFFF);
            int s2 = (int)(q2 & 0x1FFFF), s3 = (int)(q3 & 0x1FFFF);
            float w0 = __uint_as_float((uint)(q0 >> 32));
            float w1 = __uint_as_float((uint)(q1 >> 32));
            float w2 = __uint_as_float((uint)(q2 >> 32));
            float w3 = __uint_as_float((uint)(q3 >> 32));
            uint4 v0 = *(const uint4*)&prev[(size_t)s0 * 16 + l * 8];
            uint4 v1 = *(const uint4*)&prev[(size_t)s1 * 16 + l * 8];
            uint4 v2 = *(const uint4*)&prev[(size_t)s2 * 16 + l * 8];
            uint4 v3 = *(const uint4*)&prev[(size_t)s3 * 16 + l * 8];
            a[0] += w0 * bflo(v0.x); a[1] += w0 * bfhi(v0.x);
            a[2] += w0 * bflo(v0.y); a[3] += w0 * bfhi(v0.y);
            a[4] += w0 * bflo(v0.z); a[5] += w0 * bfhi(v0.z);
            a[6] += w0 * bflo(v0.w); a[7] += w0 * bfhi(v0.w);
            a[0] += w1 * bflo(v1.x); a[1] += w1 * bfhi(v1.x);
            a[2] += w1 * bflo(v1.y); a[3] += w1 * bfhi(v1.y);
            a[4] += w1 * bflo(v1.z); a[5] += w1 * bfhi(v1.z);
            a[6] += w1 * bflo(v1.w); a[7] += w1 * bfhi(v1.w);
            a[0] += w2 * bflo(v2.x); a[1] += w2 * bfhi(v2.x);
            a[2] += w2 * bflo(v2.y); a[3] += w2 * bfhi(v2.y);
            a[4] += w2 * bflo(v2.z); a[5] += w2 * bfhi(v2.z);
            a[6] += w2 * bflo(v2.w); a[7] += w2 * bfhi(v2.w);
            a[0] += w3 * bflo(v3.x); a[1] += w3 * bfhi(v3.x);
            a[2] += w3 * bflo(v3.y); a[3] += w3 * bfhi(v3.y);
            a[4] += w3 * bflo(v3.z); a[5] += w3 * bfhi(v3.z);
            a[6] += w3 * bflo(v3.w); a[7] += w3 * bfhi(v3.w);
            e = en;
            if (!more) break;
            q0 = p0; q1 = p1; q2 = p2; q3 = p3;
        }
    }
    // tail
    for (; e < e1; e += 4) {
        long long q0 = __builtin_nontemporal_load(csrq + e);
        int s0 = (int)(q0 & 0x1FFFF);
        float w0 = __uint_as_float((uint)(q0 >> 32));
        uint4 v0 = *(const uint4*)&prev[(size_t)s0 * 16 + l * 8];
        a[0] += w0 * bflo(v0.x); a[1] += w0 * bfhi(v0.x);
        a[2] += w0 * bflo(v0.y); a[3] += w0 * bfhi(v0.y);
        a[4] += w0 * bflo(v0.z); a[5] += w0 * bfhi(v0.z);
        a[6] += w0 * bflo(v0.w); a[7] += w0 * bfhi(v0.w);
    }

#pragma unroll
    for (int d = 2; d <= 4; d <<= 1) {
#pragma unroll
        for (int j = 0; j < 8; ++j) a[j] += __shfl_xor(a[j], d);
    }

    if (g == 0) {
        uint4 nv = make_uint4(pk2(a[0], a[1]), pk2(a[2], a[3]),
                              pk2(a[4], a[5]), pk2(a[6], a[7]));
        *(uint4*)&next[(size_t)n * 16 + l * 8] = nv;
    }
}

// ---------------------------------------------------------------------------
// Final combine: out[n] = sum_k sigmoid(hops[k][n].pw + pb) * hops[k][n].
// 2 lanes/node, 11 independent 16B loads in flight per lane.
// ---------------------------------------------------------------------------
__global__ __launch_bounds__(256) void combine_all(
    const ushort* __restrict__ hops,   // (K+1) buffers, stride N*16
    const float* __restrict__ pw, const float* __restrict__ pb,
    float* __restrict__ out)
{
    const int t = threadIdx.x;
    const int l = t & 1;
    const int n = blockIdx.x * 128 + (t >> 1);
    if (n >= N_NODES) return;
    float4 p0 = ((const float4*)pw)[l * 2];
    float4 p1 = ((const float4*)pw)[l * 2 + 1];
    const float pb0 = pb[0];
    float o0 = 0.f, o1 = 0.f, o2 = 0.f, o3 = 0.f;
    float o4 = 0.f, o5 = 0.f, o6 = 0.f, o7 = 0.f;
#pragma unroll
    for (int k = 0; k <= K_HOPS; ++k) {
        uint4 v = *(const uint4*)
            &hops[((size_t)k * N_NODES + n) * 16 + l * 8];
        float a0 = bflo(v.x), a1 = bfhi(v.x), a2 = bflo(v.y), a3 = bfhi(v.y);
        float a4 = bflo(v.z), a5 = bfhi(v.z), a6 = bflo(v.w), a7 = bfhi(v.w);
        float part = a0*p0.x + a1*p0.y + a2*p0.z + a3*p0.w
                   + a4*p1.x + a5*p1.y + a6*p1.z + a7*p1.w;
        part += __shfl_xor(part, 1);
        float s = 1.f / (1.f + __expf(-(part + pb0)));
        o0 += s*a0; o1 += s*a1; o2 += s*a2; o3 += s*a3;
        o4 += s*a4; o5 += s*a5; o6 += s*a6; o7 += s*a7;
    }
    *(float4*)&out[(size_t)n * 16 + l * 8]     = make_float4(o0, o1, o2, o3);
    *(float4*)&out[(size_t)n * 16 + l * 8 + 4] = make_float4(o4, o5, o6, o7);
}

// ---------------------------------------------------------------------------
extern "C" void kernel_launch(void* const* d_in, const int* in_sizes, int n_in,
                              void* d_out, int out_size, void* d_ws, size_t ws_size,
                              hipStream_t stream)
{
    const float* x  = (const float*)d_in[0];
    const int*   ei = (const int*)d_in[1];
    const float* ea = (const float*)d_in[2];
    const float* w1 = (const float*)d_in[3];
    const float* b1 = (const float*)d_in[4];
    const float* w2 = (const float*)d_in[5];
    const float* b2 = (const float*)d_in[6];
    const float* w3 = (const float*)d_in[7];
    const float* b3 = (const float*)d_in[8];
    const float* pw = (const float*)d_in[9];
    const float* pb = (const float*)d_in[10];
    float* out = (float*)d_out;

    char* ws = (char*)d_ws;
    size_t off = 0;
    char*   region0 = ws + off;           off += (size_t)E_EDGES * 16;       // 51.2 MB
    int*    rowp  = (int*)(ws + off);     off += (((size_t)(N_NODES + 1) * 4) + 15) & ~(size_t)15;
    int*    cmat  = (int*)(ws + off);     off += ((size_t)NFLAT * 4 + 15) & ~(size_t)15;  // 1.22 MB
    int*    bsum  = (int*)(ws + off);     off += ((size_t)GA * 4 + 15) & ~(size_t)15;
    int*    boff  = (int*)(ws + off);     off += ((size_t)GA * 4 + 15) & ~(size_t)15;
    int*    pbase = (int*)(ws + off);     off += ((size_t)(NPART + 1) * 4 + 15) & ~(size_t)15;
    int2*   csr   = (int2*)(ws + off);    off += (size_t)E_EDGES * 8;        // 25.6 MB

    // staging (25.6MB) lives in region0 during CSR build; afterwards region0
    // holds the 11 hop-state buffers (11 x 3.2MB = 35.2MB <= 51.2MB).
    // Stream-ordered: partition_build finishes staging reads before
    // fused_mlp writes hops[0].
    int2*   staging = (int2*)region0;
    ushort* hops    = (ushort*)region0;
    const size_t HSTRIDE = (size_t)N_NODES * 16;   // ushorts per hop buffer

    const int* src = ei;
    const int* dst = ei + E_EDGES;

    const dim3 blk(256);
    const int mlpGrid    = (N_NODES + 127) / 128;   // 782
    const int hopGrid    = (N_NODES + 31) / 32;     // 3125

    // ---- CSR build: contention-free multi-split ----
    hist2<<<NCHUNK, blk, 0, stream>>>(dst, cmat);
    scan_reduce<<<GA, 1024, 0, stream>>>(cmat, bsum);
    scan_tops<<<1, 64, 0, stream>>>(bsum, boff);
    scan_apply<<<GA, 1024, 0, stream>>>(cmat, boff, pbase);
    scatter3<<<NCHUNK, blk, 0, stream>>>(src, dst, ea, cmat, staging);
    partition_build<<<NPART, 1024, 0, stream>>>(staging, pbase, rowp, csr);

    // ---- fused MLP (3 layers) -> hops[0] ----
    fused_mlp<<<mlpGrid, blk, 0, stream>>>(x, w1, b1, w2, b2, w3, b3, hops);

    // ---- K hops (gather only; nt+prefetched csr stream) ----
    for (int k = 0; k < K_HOPS; ++k) {
        hop_bf16<<<hopGrid, blk, 0, stream>>>(hops + (size_t)k * HSTRIDE,
                                              hops + (size_t)(k + 1) * HSTRIDE,
                                              rowp, csr);
    }

    // ---- final combine over all K+1 states ----
    combine_all<<<mlpGrid, blk, 0, stream>>>(hops, pw, pb, out);
}

// Round 12
// 573.827 us; speedup vs baseline: 1.1678x; 1.1370x over previous
//
#include <hip/hip_runtime.h>
#include <hip/hip_bf16.h>
#include <math.h>

#define N_NODES 100000
#define E_EDGES 3200000
#define K_HOPS  10
#define NPP     256                          // nodes per partition (dst>>8)
#define NPART   ((N_NODES + NPP - 1) / NPP)  // 391 partitions
#define CHUNK   4096                         // edges per scatter block
#define EPT     (CHUNK / 256)                // 16 edges per thread
#define NCHUNK  ((E_EDGES + CHUNK - 1) / CHUNK)   // 782 chunks
#define NFLAT   (NPART * NCHUNK)                  // 305762
#define SSEG    8192
#define GA      ((NFLAT + SSEG - 1) / SSEG)       // 38 scan blocks

typedef __attribute__((ext_vector_type(8))) short short8;
typedef __attribute__((ext_vector_type(4))) float floatx4;

__device__ __forceinline__ ushort f2bf(float f) {
    uint u = __float_as_uint(f);
    u += 0x7fffu + ((u >> 16) & 1u);
    return (ushort)(u >> 16);
}
__device__ __forceinline__ uint pk2(float a, float b) {
    return (uint)f2bf(a) | ((uint)f2bf(b) << 16);
}
__device__ __forceinline__ float bflo(uint u) { return __uint_as_float(u << 16); }
__device__ __forceinline__ float bfhi(uint u) { return __uint_as_float(u & 0xffff0000u); }

// ---------------------------------------------------------------------------
// Fused 3-layer MLP (256->128->128->16, relu). Writes bf16 h3 -> hops[0].
// One block = 128 rows, 4 waves x 32 rows. h1/h2 never leave LDS.
// r12 variant: HALF-WINDOW X prefetch (afr[2][4] = 32 VGPRs, reloaded once
// mid-layer-1) to fit __launch_bounds__(256,3): peak live ~124 VGPRs < ~168
// cap -> 3 blocks/CU (vs 2 at the r5 full-prefetch (256,2) version, 64us).
// History: full 64-VGPR prefetch spilled at (256,3) [r1/r2: VGPR=84,
// WRITE+51MB] and (256,4) [r7: VGPR=64, WRITE+11MB]. Spill check: mlp row
// VGPR<=100 AND WRITE_SIZE>=10MB -> revert to (256,2) full prefetch.
// LDS tiles XOR-swizzled: col ^= (row&7)<<3 (ushort units, 16B groups).
// ---------------------------------------------------------------------------
__global__ __launch_bounds__(256, 3) void fused_mlp(
    const float* __restrict__ X,
    const float* __restrict__ W1, const float* __restrict__ B1,
    const float* __restrict__ W2, const float* __restrict__ B2,
    const float* __restrict__ W3, const float* __restrict__ B3,
    ushort* __restrict__ H0)      // hops[0]: N x 16 bf16
{
    __shared__ ushort Wl[128 * 64];    // 16 KB: W slice (128 rows x 64 cols bf16)
    __shared__ ushort Hb[128 * 128];   // 32 KB: h tile  (128 rows x 128 cols bf16)

    const int t    = threadIdx.x;
    const int w    = t >> 6;
    const int lane = t & 63;
    const int m    = lane & 15;
    const int quad = lane >> 4;
    const int rowBase = blockIdx.x * 128 + w * 32;
    const int swm = (m & 7) << 3;      // row-swizzle term for fragment reads

    int xrow[2];
#pragma unroll
    for (int rt = 0; rt < 2; ++rt) {
        int row = rowBase + rt * 16 + m;
        xrow[rt] = row < N_NODES ? row : N_NODES - 1;
    }

    // ---- prefetch FIRST HALF of layer-1 A (k 0..127): 16x16B loads in flight
    short8 afr[2][4];
#pragma unroll
    for (int rt = 0; rt < 2; ++rt) {
        const float* xp = X + (size_t)xrow[rt] * 256 + quad * 8;
#pragma unroll
        for (int kk = 0; kk < 4; ++kk) {
            floatx4 a0 = *(const floatx4*)(xp + kk * 32);
            floatx4 a1 = *(const floatx4*)(xp + kk * 32 + 4);
            short8 v;
            v[0] = (short)f2bf(a0[0]); v[1] = (short)f2bf(a0[1]);
            v[2] = (short)f2bf(a0[2]); v[3] = (short)f2bf(a0[3]);
            v[4] = (short)f2bf(a1[0]); v[5] = (short)f2bf(a1[1]);
            v[6] = (short)f2bf(a1[2]); v[7] = (short)f2bf(a1[3]);
            afr[rt][kk] = v;
        }
    }

    floatx4 acc[2][8];
#pragma unroll
    for (int rt = 0; rt < 2; ++rt)
#pragma unroll
        for (int ct = 0; ct < 8; ++ct) acc[rt][ct] = (floatx4)0.f;

    // ================= Layer 1 first half: k 0..127 =================
#pragma unroll
    for (int kb4 = 0; kb4 < 2; ++kb4) {
#pragma unroll
        for (int j = 0; j < 8; ++j) {
            int flat = j * 256 + t;
            int n  = flat >> 4;
            int c4 = (flat & 15) * 4;
            floatx4 v = *(const floatx4*)&W1[(size_t)n * 256 + kb4 * 64 + c4];
            *(uint2*)&Wl[n * 64 + (c4 ^ ((n & 7) << 3))] =
                make_uint2(pk2(v[0], v[1]), pk2(v[2], v[3]));
        }
        __syncthreads();
#pragma unroll
        for (int ks = 0; ks < 2; ++ks) {
#pragma unroll
            for (int ct = 0; ct < 8; ++ct) {
                short8 bf = *(const short8*)
                    &Wl[(ct * 16 + m) * 64 + ((ks * 32 + quad * 8) ^ swm)];
                acc[0][ct] = __builtin_amdgcn_mfma_f32_16x16x32_bf16(
                    afr[0][kb4 * 2 + ks], bf, acc[0][ct], 0, 0, 0);
                acc[1][ct] = __builtin_amdgcn_mfma_f32_16x16x32_bf16(
                    afr[1][kb4 * 2 + ks], bf, acc[1][ct], 0, 0, 0);
            }
        }
        __syncthreads();
    }

    // ---- prefetch SECOND HALF of layer-1 A (k 128..255) into same regs
#pragma unroll
    for (int rt = 0; rt < 2; ++rt) {
        const float* xp = X + (size_t)xrow[rt] * 256 + 128 + quad * 8;
#pragma unroll
        for (int kk = 0; kk < 4; ++kk) {
            floatx4 a0 = *(const floatx4*)(xp + kk * 32);
            floatx4 a1 = *(const floatx4*)(xp + kk * 32 + 4);
            short8 v;
            v[0] = (short)f2bf(a0[0]); v[1] = (short)f2bf(a0[1]);
            v[2] = (short)f2bf(a0[2]); v[3] = (short)f2bf(a0[3]);
            v[4] = (short)f2bf(a1[0]); v[5] = (short)f2bf(a1[1]);
            v[6] = (short)f2bf(a1[2]); v[7] = (short)f2bf(a1[3]);
            afr[rt][kk] = v;
        }
    }

    // ================= Layer 1 second half: k 128..255 =================
#pragma unroll
    for (int kb4 = 2; kb4 < 4; ++kb4) {
#pragma unroll
        for (int j = 0; j < 8; ++j) {
            int flat = j * 256 + t;
            int n  = flat >> 4;
            int c4 = (flat & 15) * 4;
            floatx4 v = *(const floatx4*)&W1[(size_t)n * 256 + kb4 * 64 + c4];
            *(uint2*)&Wl[n * 64 + (c4 ^ ((n & 7) << 3))] =
                make_uint2(pk2(v[0], v[1]), pk2(v[2], v[3]));
        }
        __syncthreads();
#pragma unroll
        for (int ks = 0; ks < 2; ++ks) {
#pragma unroll
            for (int ct = 0; ct < 8; ++ct) {
                short8 bf = *(const short8*)
                    &Wl[(ct * 16 + m) * 64 + ((ks * 32 + quad * 8) ^ swm)];
                acc[0][ct] = __builtin_amdgcn_mfma_f32_16x16x32_bf16(
                    afr[0][(kb4 - 2) * 2 + ks], bf, acc[0][ct], 0, 0, 0);
                acc[1][ct] = __builtin_amdgcn_mfma_f32_16x16x32_bf16(
                    afr[1][(kb4 - 2) * 2 + ks], bf, acc[1][ct], 0, 0, 0);
            }
        }
        __syncthreads();
    }

    // h1 = relu(acc + b1) -> Hb (bf16, swizzled). Each wave owns its 32 rows.
    {
        float br[8];
#pragma unroll
        for (int ct = 0; ct < 8; ++ct) br[ct] = B1[ct * 16 + m];
#pragma unroll
        for (int rt = 0; rt < 2; ++rt)
#pragma unroll
            for (int r = 0; r < 4; ++r) {
                int lrow = w * 32 + rt * 16 + quad * 4 + r;
                int sw = (lrow & 7) << 3;
#pragma unroll
                for (int ct = 0; ct < 8; ++ct) {
                    float v = acc[rt][ct][r] + br[ct];
                    v = v > 0.f ? v : 0.f;
                    Hb[lrow * 128 + ((ct * 16 + m) ^ sw)] = f2bf(v);
                }
            }
    }

#pragma unroll
    for (int rt = 0; rt < 2; ++rt)
#pragma unroll
        for (int ct = 0; ct < 8; ++ct) acc[rt][ct] = (floatx4)0.f;

    // ================= Layer 2: h1(128) -> h2(128) =================
#pragma unroll
    for (int kb2 = 0; kb2 < 2; ++kb2) {
#pragma unroll
        for (int j = 0; j < 8; ++j) {
            int flat = j * 256 + t;
            int n  = flat >> 4;
            int c4 = (flat & 15) * 4;
            floatx4 v = *(const floatx4*)&W2[(size_t)n * 128 + kb2 * 64 + c4];
            *(uint2*)&Wl[n * 64 + (c4 ^ ((n & 7) << 3))] =
                make_uint2(pk2(v[0], v[1]), pk2(v[2], v[3]));
        }
        __syncthreads();   // also makes this wave's Hb writes safely ordered
#pragma unroll
        for (int ks = 0; ks < 2; ++ks) {
            short8 af[2];
#pragma unroll
            for (int rt = 0; rt < 2; ++rt) {
                int lrow = w * 32 + rt * 16 + m;
                int col  = kb2 * 64 + ks * 32 + quad * 8;
                af[rt] = *(const short8*)&Hb[lrow * 128 + (col ^ swm)];
            }
#pragma unroll
            for (int ct = 0; ct < 8; ++ct) {
                short8 bf = *(const short8*)
                    &Wl[(ct * 16 + m) * 64 + ((ks * 32 + quad * 8) ^ swm)];
                acc[0][ct] = __builtin_amdgcn_mfma_f32_16x16x32_bf16(
                    af[0], bf, acc[0][ct], 0, 0, 0);
                acc[1][ct] = __builtin_amdgcn_mfma_f32_16x16x32_bf16(
                    af[1], bf, acc[1][ct], 0, 0, 0);
            }
        }
        __syncthreads();
    }

    // h2 = relu(acc + b2) -> Hb (overwrite own rows; reads drained by barrier)
    {
        float br[8];
#pragma unroll
        for (int ct = 0; ct < 8; ++ct) br[ct] = B2[ct * 16 + m];
#pragma unroll
        for (int rt = 0; rt < 2; ++rt)
#pragma unroll
            for (int r = 0; r < 4; ++r) {
                int lrow = w * 32 + rt * 16 + quad * 4 + r;
                int sw = (lrow & 7) << 3;
#pragma unroll
                for (int ct = 0; ct < 8; ++ct) {
                    float v = acc[rt][ct][r] + br[ct];
                    v = v > 0.f ? v : 0.f;
                    Hb[lrow * 128 + ((ct * 16 + m) ^ sw)] = f2bf(v);
                }
            }
    }

    // ================= Layer 3: h2(128) -> h3(16) =================
    // stage all of W3 (16 x 128) bf16, swizzled
#pragma unroll
    for (int j = 0; j < 2; ++j) {
        int flat = j * 256 + t;
        int n  = flat >> 5;          // 0..15
        int c4 = (flat & 31) * 4;    // 0..124
        floatx4 v = *(const floatx4*)&W3[(size_t)n * 128 + c4];
        *(uint2*)&Wl[n * 128 + (c4 ^ ((n & 7) << 3))] =
            make_uint2(pk2(v[0], v[1]), pk2(v[2], v[3]));
    }
    __syncthreads();

    floatx4 acc3[2];
    acc3[0] = (floatx4)0.f; acc3[1] = (floatx4)0.f;
#pragma unroll
    for (int ks4 = 0; ks4 < 4; ++ks4) {
        int col = ks4 * 32 + quad * 8;
        short8 bf = *(const short8*)&Wl[m * 128 + (col ^ swm)];
#pragma unroll
        for (int rt = 0; rt < 2; ++rt) {
            int lrow = w * 32 + rt * 16 + m;
            short8 af = *(const short8*)&Hb[lrow * 128 + (col ^ swm)];
            acc3[rt] = __builtin_amdgcn_mfma_f32_16x16x32_bf16(
                af, bf, acc3[rt], 0, 0, 0);
        }
    }

    // ---- epilogue: h3 = relu(acc3+b3) -> hops[0] (scoring in combine_all)
    const float b3m = B3[m];
#pragma unroll
    for (int rt = 0; rt < 2; ++rt)
#pragma unroll
        for (int r = 0; r < 4; ++r) {
            int row = rowBase + rt * 16 + quad * 4 + r;
            float v = acc3[rt][r] + b3m;
            v = v > 0.f ? v : 0.f;
            if (row < N_NODES) H0[(size_t)row * 16 + m] = f2bf(v);
        }
}

// ---------------------------------------------------------------------------
// CSR stage 1: per-chunk per-partition histogram -> cmat[p*NCHUNK + chunk]
// ---------------------------------------------------------------------------
__global__ __launch_bounds__(256) void hist2(
    const int* __restrict__ dst, int* __restrict__ cmat)
{
    __shared__ int lhist[NPART];
    const int t = threadIdx.x;
    for (int p = t; p < NPART; p += 256) lhist[p] = 0;
    __syncthreads();
    const int base = blockIdx.x * CHUNK;
#pragma unroll
    for (int j = 0; j < EPT; ++j) {
        int i = base + j * 256 + t;
        if (i < E_EDGES) atomicAdd(&lhist[dst[i] >> 8], 1);
    }
    __syncthreads();
    for (int p = t; p < NPART; p += 256)
        cmat[p * NCHUNK + blockIdx.x] = lhist[p];
}

// ---------------------------------------------------------------------------
// Scan level A: per-8192-segment reduction -> bsum
// ---------------------------------------------------------------------------
__global__ __launch_bounds__(1024) void scan_reduce(
    const int* __restrict__ cmat, int* __restrict__ bsum)
{
    __shared__ int wsum[16];
    const int t = threadIdx.x, lane = t & 63, wid = t >> 6;
    int base = blockIdx.x * SSEG + t * 8;
    int s = 0;
#pragma unroll
    for (int j = 0; j < 8; ++j) {
        int idx = base + j;
        if (idx < NFLAT) s += cmat[idx];
    }
#pragma unroll
    for (int d = 1; d < 64; d <<= 1) s += __shfl_xor(s, d);
    if (lane == 0) wsum[wid] = s;
    __syncthreads();
    if (t == 0) {
        int tot = 0;
#pragma unroll
        for (int i = 0; i < 16; ++i) tot += wsum[i];
        bsum[blockIdx.x] = tot;
    }
}

// ---------------------------------------------------------------------------
// Scan level B: exclusive scan of GA block sums (single wave)
// ---------------------------------------------------------------------------
__global__ void scan_tops(const int* __restrict__ bsum, int* __restrict__ boff)
{
    const int t = threadIdx.x;
    int v = (t < GA) ? bsum[t] : 0;
    int x = v;
#pragma unroll
    for (int d = 1; d < 64; d <<= 1) {
        int y = __shfl_up(x, d);
        if (t >= d) x += y;
    }
    if (t < GA) boff[t] = x - v;
}

// ---------------------------------------------------------------------------
// Scan level C: full exclusive scan applied in-place; also emits pbase[].
// ---------------------------------------------------------------------------
__global__ __launch_bounds__(1024) void scan_apply(
    int* __restrict__ cmat, const int* __restrict__ boff, int* __restrict__ pbase)
{
    __shared__ int wsum[16];
    __shared__ int woff[17];
    const int t = threadIdx.x, lane = t & 63, wid = t >> 6;
    int base = blockIdx.x * SSEG + t * 8;
    int v[8], pre[8];
    int s = 0;
#pragma unroll
    for (int j = 0; j < 8; ++j) {
        int idx = base + j;
        v[j] = (idx < NFLAT) ? cmat[idx] : 0;
        pre[j] = s;
        s += v[j];
    }
    int x = s;
#pragma unroll
    for (int d = 1; d < 64; d <<= 1) {
        int y = __shfl_up(x, d);
        if (lane >= d) x += y;
    }
    if (lane == 63) wsum[wid] = x;
    __syncthreads();
    if (wid == 0) {
        int w = (lane < 16) ? wsum[lane] : 0;
#pragma unroll
        for (int d = 1; d < 16; d <<= 1) {
            int y = __shfl_up(w, d);
            if (lane >= d) w += y;
        }
        if (lane < 16) woff[lane + 1] = w;
        if (lane == 0) woff[0] = 0;
    }
    __syncthreads();
    int tbase = boff[blockIdx.x] + woff[wid] + (x - s);
#pragma unroll
    for (int j = 0; j < 8; ++j) {
        int idx = base + j;
        if (idx < NFLAT) {
            int e = tbase + pre[j];
            cmat[idx] = e;
            if (idx % NCHUNK == 0) pbase[idx / NCHUNK] = e;
        }
    }
    if (blockIdx.x == 0 && t == 0) pbase[NPART] = E_EDGES;
}

// ---------------------------------------------------------------------------
// CSR stage 2: LDS-sorted scatter.
// ---------------------------------------------------------------------------
__global__ __launch_bounds__(256) void scatter3(
    const int* __restrict__ src, const int* __restrict__ dst,
    const float* __restrict__ ea, const int* __restrict__ cbase,
    int2* __restrict__ staging)
{
    __shared__ int2 ebuf[CHUNK];     // 32 KB sorted entries
    __shared__ int  gaddr[CHUNK];    // 16 KB global positions
    __shared__ int  lcnt[NPART];     // counts -> cursors (local sorted idx)
    __shared__ int  goff[NPART];     // global pos = goff[p] + local idx
    __shared__ int  wsum[4];
    const int t = threadIdx.x;
    const int b = blockIdx.x;
    const int base = b * CHUNK;
    const int cnt = min(CHUNK, E_EDGES - base);
    const int lane = t & 63, wid = t >> 6;

    for (int p = t; p < NPART; p += 256) lcnt[p] = 0;
    __syncthreads();

    int d[EPT];
#pragma unroll
    for (int j = 0; j < EPT; ++j) {
        int i = base + j * 256 + t;
        d[j] = (i < E_EDGES) ? dst[i] : -1;
        if (d[j] >= 0) atomicAdd(&lcnt[d[j] >> 8], 1);
    }
    __syncthreads();

    int v0 = (2 * t     < NPART) ? lcnt[2 * t]     : 0;
    int v1 = (2 * t + 1 < NPART) ? lcnt[2 * t + 1] : 0;
    int pair = v0 + v1;
    int x = pair;
#pragma unroll
    for (int dd = 1; dd < 64; dd <<= 1) {
        int y = __shfl_up(x, dd);
        if (lane >= dd) x += y;
    }
    if (lane == 63) wsum[wid] = x;
    __syncthreads();
    int wbase = 0;
#pragma unroll
    for (int w = 0; w < 4; ++w) if (w < wid) wbase += wsum[w];
    int excl = wbase + x - pair;
    if (2 * t < NPART) {
        lcnt[2 * t] = excl;
        goff[2 * t] = cbase[(2 * t) * NCHUNK + b] - excl;
    }
    if (2 * t + 1 < NPART) {
        lcnt[2 * t + 1] = excl + v0;
        goff[2 * t + 1] = cbase[(2 * t + 1) * NCHUNK + b] - (excl + v0);
    }
    __syncthreads();

#pragma unroll
    for (int j = 0; j < EPT; ++j) {
        if (d[j] >= 0) {
            int i = base + j * 256 + t;
            int p = d[j] >> 8;
            int s = atomicAdd(&lcnt[p], 1);
            ebuf[s]  = make_int2(__float_as_int(ea[i]),
                                 src[i] | ((d[j] & 255) << 17));
            gaddr[s] = goff[p] + s;
        }
    }
    __syncthreads();

    for (int k = t; k < cnt; k += 256)
        staging[gaddr[k]] = ebuf[k];
}

// ---------------------------------------------------------------------------
// CSR stage 3: one 1024-thread block per partition -> rowp + final CSR.
// ---------------------------------------------------------------------------
__global__ __launch_bounds__(1024) void partition_build(
    const int2* __restrict__ staging, const int* __restrict__ pbase,
    int* __restrict__ rowp, int2* __restrict__ csr)
{
    __shared__ int ncnt[NPP];
    __shared__ int wsum[4];
    const int p = blockIdx.x;
    const int t = threadIdx.x;
    const int e0 = pbase[p], e1 = pbase[p + 1];
    const int cnt = e1 - e0;
    const int n0 = p << 8;

    if (t < NPP) ncnt[t] = 0;
    __syncthreads();
    for (int e = t; e < cnt; e += 1024)
        atomicAdd(&ncnt[(staging[e0 + e].y >> 17) & 255], 1);
    __syncthreads();

    int x = 0, v = 0;
    if (t < NPP) {
        const int lane = t & 63, wid = t >> 6;
        v = ncnt[t];
        x = v;
#pragma unroll
        for (int d = 1; d < 64; d <<= 1) {
            int y = __shfl_up(x, d);
            if (lane >= d) x += y;
        }
        if (lane == 63) wsum[wid] = x;
    }
    __syncthreads();
    if (t < NPP) {
        const int wid = t >> 6;
        int wbase = 0;
#pragma unroll
        for (int w = 0; w < 4; ++w) if (w < wid) wbase += wsum[w];
        int excl = wbase + x - v;
        ncnt[t] = e0 + excl;
        int n = n0 + t;
        if (n < N_NODES) rowp[n] = e0 + excl;
    }
    if (p == NPART - 1 && t == 0) rowp[N_NODES] = E_EDGES;
    __syncthreads();

    for (int e = t; e < cnt; e += 1024) {
        int2 en = staging[e0 + e];
        int dlo = (en.y >> 17) & 255;
        int pos = atomicAdd(&ncnt[dlo], 1);
        csr[pos] = make_int2(en.y & 0x1FFFF, en.x);
    }
}

// ---------------------------------------------------------------------------
// One hop (bf16 states), gather only. 8 lanes/node, 4 gathers in flight.
// r5-EXACT form (plain loads). Verified best: ~43us/hop. Failed variants:
// r4 8-deep ILP (null), r6 LDS-atomic (7x worse), r9 nt (+25%), r11
// nt+prefetch (+20%). The hop is at its divergent-gather HW floor for
// bf16 states; do not re-tune the load path.
// ---------------------------------------------------------------------------
__global__ __launch_bounds__(256) void hop_bf16(
    const ushort* __restrict__ prev, ushort* __restrict__ next,
    const int* __restrict__ rowp, const int2* __restrict__ csr)
{
    const int t = threadIdx.x;
    const int l = t & 1;
    const int g = (t >> 1) & 3;
    const int n = blockIdx.x * 32 + (t >> 3);
    if (n >= N_NODES) return;
    const int e0 = rowp[n], e1 = rowp[n + 1];
    float a[8];
#pragma unroll
    for (int j = 0; j < 8; ++j) a[j] = 0.f;

    int e = e0 + g;
    for (; e + 12 < e1; e += 16) {
        int2 c0 = csr[e];
        int2 c1 = csr[e + 4];
        int2 c2 = csr[e + 8];
        int2 c3 = csr[e + 12];
        float w0 = __int_as_float(c0.y), w1 = __int_as_float(c1.y);
        float w2 = __int_as_float(c2.y), w3 = __int_as_float(c3.y);
        uint4 v0 = *(const uint4*)&prev[(size_t)c0.x * 16 + l * 8];
        uint4 v1 = *(const uint4*)&prev[(size_t)c1.x * 16 + l * 8];
        uint4 v2 = *(const uint4*)&prev[(size_t)c2.x * 16 + l * 8];
        uint4 v3 = *(const uint4*)&prev[(size_t)c3.x * 16 + l * 8];
        a[0] += w0 * bflo(v0.x); a[1] += w0 * bfhi(v0.x);
        a[2] += w0 * bflo(v0.y); a[3] += w0 * bfhi(v0.y);
        a[4] += w0 * bflo(v0.z); a[5] += w0 * bfhi(v0.z);
        a[6] += w0 * bflo(v0.w); a[7] += w0 * bfhi(v0.w);
        a[0] += w1 * bflo(v1.x); a[1] += w1 * bfhi(v1.x);
        a[2] += w1 * bflo(v1.y); a[3] += w1 * bfhi(v1.y);
        a[4] += w1 * bflo(v1.z); a[5] += w1 * bfhi(v1.z);
        a[6] += w1 * bflo(v1.w); a[7] += w1 * bfhi(v1.w);
        a[0] += w2 * bflo(v2.x); a[1] += w2 * bfhi(v2.x);
        a[2] += w2 * bflo(v2.y); a[3] += w2 * bfhi(v2.y);
        a[4] += w2 * bflo(v2.z); a[5] += w2 * bfhi(v2.z);
        a[6] += w2 * bflo(v2.w); a[7] += w2 * bfhi(v2.w);
        a[0] += w3 * bflo(v3.x); a[1] += w3 * bfhi(v3.x);
        a[2] += w3 * bflo(v3.y); a[3] += w3 * bfhi(v3.y);
        a[4] += w3 * bflo(v3.z); a[5] += w3 * bfhi(v3.z);
        a[6] += w3 * bflo(v3.w); a[7] += w3 * bfhi(v3.w);
    }
    for (; e < e1; e += 4) {
        int2 c0 = csr[e];
        float w0 = __int_as_float(c0.y);
        uint4 v0 = *(const uint4*)&prev[(size_t)c0.x * 16 + l * 8];
        a[0] += w0 * bflo(v0.x); a[1] += w0 * bfhi(v0.x);
        a[2] += w0 * bflo(v0.y); a[3] += w0 * bfhi(v0.y);
        a[4] += w0 * bflo(v0.z); a[5] += w0 * bfhi(v0.z);
        a[6] += w0 * bflo(v0.w); a[7] += w0 * bfhi(v0.w);
    }

#pragma unroll
    for (int d = 2; d <= 4; d <<= 1) {
#pragma unroll
        for (int j = 0; j < 8; ++j) a[j] += __shfl_xor(a[j], d);
    }

    if (g == 0) {
        uint4 nv = make_uint4(pk2(a[0], a[1]), pk2(a[2], a[3]),
                              pk2(a[4], a[5]), pk2(a[6], a[7]));
        *(uint4*)&next[(size_t)n * 16 + l * 8] = nv;
    }
}

// ---------------------------------------------------------------------------
// Final combine: out[n] = sum_k sigmoid(hops[k][n].pw + pb) * hops[k][n].
// 2 lanes/node, 11 independent 16B loads in flight per lane.
// ---------------------------------------------------------------------------
__global__ __launch_bounds__(256) void combine_all(
    const ushort* __restrict__ hops,   // (K+1) buffers, stride N*16
    const float* __restrict__ pw, const float* __restrict__ pb,
    float* __restrict__ out)
{
    const int t = threadIdx.x;
    const int l = t & 1;
    const int n = blockIdx.x * 128 + (t >> 1);
    if (n >= N_NODES) return;
    float4 p0 = ((const float4*)pw)[l * 2];
    float4 p1 = ((const float4*)pw)[l * 2 + 1];
    const float pb0 = pb[0];
    float o0 = 0.f, o1 = 0.f, o2 = 0.f, o3 = 0.f;
    float o4 = 0.f, o5 = 0.f, o6 = 0.f, o7 = 0.f;
#pragma unroll
    for (int k = 0; k <= K_HOPS; ++k) {
        uint4 v = *(const uint4*)
            &hops[((size_t)k * N_NODES + n) * 16 + l * 8];
        float a0 = bflo(v.x), a1 = bfhi(v.x), a2 = bflo(v.y), a3 = bfhi(v.y);
        float a4 = bflo(v.z), a5 = bfhi(v.z), a6 = bflo(v.w), a7 = bfhi(v.w);
        float part = a0*p0.x + a1*p0.y + a2*p0.z + a3*p0.w
                   + a4*p1.x + a5*p1.y + a6*p1.z + a7*p1.w;
        part += __shfl_xor(part, 1);
        float s = 1.f / (1.f + __expf(-(part + pb0)));
        o0 += s*a0; o1 += s*a1; o2 += s*a2; o3 += s*a3;
        o4 += s*a4; o5 += s*a5; o6 += s*a6; o7 += s*a7;
    }
    *(float4*)&out[(size_t)n * 16 + l * 8]     = make_float4(o0, o1, o2, o3);
    *(float4*)&out[(size_t)n * 16 + l * 8 + 4] = make_float4(o4, o5, o6, o7);
}

// ---------------------------------------------------------------------------
extern "C" void kernel_launch(void* const* d_in, const int* in_sizes, int n_in,
                              void* d_out, int out_size, void* d_ws, size_t ws_size,
                              hipStream_t stream)
{
    const float* x  = (const float*)d_in[0];
    const int*   ei = (const int*)d_in[1];
    const float* ea = (const float*)d_in[2];
    const float* w1 = (const float*)d_in[3];
    const float* b1 = (const float*)d_in[4];
    const float* w2 = (const float*)d_in[5];
    const float* b2 = (const float*)d_in[6];
    const float* w3 = (const float*)d_in[7];
    const float* b3 = (const float*)d_in[8];
    const float* pw = (const float*)d_in[9];
    const float* pb = (const float*)d_in[10];
    float* out = (float*)d_out;

    char* ws = (char*)d_ws;
    size_t off = 0;
    char*   region0 = ws + off;           off += (size_t)E_EDGES * 16;       // 51.2 MB
    int*    rowp  = (int*)(ws + off);     off += (((size_t)(N_NODES + 1) * 4) + 15) & ~(size_t)15;
    int*    cmat  = (int*)(ws + off);     off += ((size_t)NFLAT * 4 + 15) & ~(size_t)15;  // 1.22 MB
    int*    bsum  = (int*)(ws + off);     off += ((size_t)GA * 4 + 15) & ~(size_t)15;
    int*    boff  = (int*)(ws + off);     off += ((size_t)GA * 4 + 15) & ~(size_t)15;
    int*    pbase = (int*)(ws + off);     off += ((size_t)(NPART + 1) * 4 + 15) & ~(size_t)15;
    int2*   csr   = (int2*)(ws + off);    off += (size_t)E_EDGES * 8;        // 25.6 MB

    // staging (25.6MB) lives in region0 during CSR build; afterwards region0
    // holds the 11 hop-state buffers (11 x 3.2MB = 35.2MB <= 51.2MB).
    // Stream-ordered: partition_build finishes staging reads before
    // fused_mlp writes hops[0].
    int2*   staging = (int2*)region0;
    ushort* hops    = (ushort*)region0;
    const size_t HSTRIDE = (size_t)N_NODES * 16;   // ushorts per hop buffer

    const int* src = ei;
    const int* dst = ei + E_EDGES;

    const dim3 blk(256);
    const int mlpGrid    = (N_NODES + 127) / 128;   // 782
    const int hopGrid    = (N_NODES + 31) / 32;     // 3125

    // ---- CSR build: contention-free multi-split ----
    hist2<<<NCHUNK, blk, 0, stream>>>(dst, cmat);
    scan_reduce<<<GA, 1024, 0, stream>>>(cmat, bsum);
    scan_tops<<<1, 64, 0, stream>>>(bsum, boff);
    scan_apply<<<GA, 1024, 0, stream>>>(cmat, boff, pbase);
    scatter3<<<NCHUNK, blk, 0, stream>>>(src, dst, ea, cmat, staging);
    partition_build<<<NPART, 1024, 0, stream>>>(staging, pbase, rowp, csr);

    // ---- fused MLP (3 layers) -> hops[0] ----
    fused_mlp<<<mlpGrid, blk, 0, stream>>>(x, w1, b1, w2, b2, w3, b3, hops);

    // ---- K hops (gather only, r5-plain load path) ----
    for (int k = 0; k < K_HOPS; ++k) {
        hop_bf16<<<hopGrid, blk, 0, stream>>>(hops + (size_t)k * HSTRIDE,
                                              hops + (size_t)(k + 1) * HSTRIDE,
                                              rowp, csr);
    }

    // ---- final combine over all K+1 states ----
    combine_all<<<mlpGrid, blk, 0, stream>>>(hops, pw, pb, out);
}

// Round 13
// 559.561 us; speedup vs baseline: 1.1976x; 1.0255x over previous
//
#include <hip/hip_runtime.h>
#include <hip/hip_bf16.h>
#include <math.h>

#define N_NODES 100000
#define E_EDGES 3200000
#define K_HOPS  10
#define NPP     256                          // nodes per partition (dst>>8)
#define NPART   ((N_NODES + NPP - 1) / NPP)  // 391 partitions
#define CHUNK   4096                         // edges per scatter block
#define EPT     (CHUNK / 256)                // 16 edges per thread
#define NCHUNK  ((E_EDGES + CHUNK - 1) / CHUNK)   // 782 chunks
#define NFLAT   (NPART * NCHUNK)                  // 305762
#define SSEG    8192
#define GA      ((NFLAT + SSEG - 1) / SSEG)       // 38 scan blocks

typedef __attribute__((ext_vector_type(8))) short short8;
typedef __attribute__((ext_vector_type(4))) float floatx4;

__device__ __forceinline__ ushort f2bf(float f) {
    uint u = __float_as_uint(f);
    u += 0x7fffu + ((u >> 16) & 1u);
    return (ushort)(u >> 16);
}
__device__ __forceinline__ uint pk2(float a, float b) {
    return (uint)f2bf(a) | ((uint)f2bf(b) << 16);
}
__device__ __forceinline__ float bflo(uint u) { return __uint_as_float(u << 16); }
__device__ __forceinline__ float bfhi(uint u) { return __uint_as_float(u & 0xffff0000u); }

// ---------------------------------------------------------------------------
// Fused 3-layer MLP (256->128->128->16, relu). Writes bf16 h3 -> hops[0].
// One block = 128 rows, 4 waves x 32 rows. h1/h2 never leave LDS.
// Layer-1 A prefetched into 64 bf16 VGPRs; (256,2) launch bounds REQUIRED.
// CLOSED KNOB (3x confirmed): any tighter cap spills the prefetch to scratch:
//   (256,3) full prefetch  r1/r2: VGPR=84,  WRITE +51MB, 121us
//   (256,4) 64-row         r7:    VGPR=64,  WRITE +11MB,  90us
//   (256,3) half-window    r12:   VGPR=84,  WRITE +22MB,  73us
// This 128-row/(256,2) version is the verified optimum: 64us, VGPR=124,
// WRITE_SIZE ideal (3.2MB). DO NOT re-tune occupancy here.
// LDS tiles XOR-swizzled: col ^= (row&7)<<3 (ushort units, 16B groups).
// ---------------------------------------------------------------------------
__global__ __launch_bounds__(256, 2) void fused_mlp(
    const float* __restrict__ X,
    const float* __restrict__ W1, const float* __restrict__ B1,
    const float* __restrict__ W2, const float* __restrict__ B2,
    const float* __restrict__ W3, const float* __restrict__ B3,
    ushort* __restrict__ H0)      // hops[0]: N x 16 bf16
{
    __shared__ ushort Wl[128 * 64];    // 16 KB: W slice (128 rows x 64 cols bf16)
    __shared__ ushort Hb[128 * 128];   // 32 KB: h tile  (128 rows x 128 cols bf16)

    const int t    = threadIdx.x;
    const int w    = t >> 6;
    const int lane = t & 63;
    const int m    = lane & 15;
    const int quad = lane >> 4;
    const int rowBase = blockIdx.x * 128 + w * 32;
    const int swm = (m & 7) << 3;      // row-swizzle term for fragment reads

    // ---- prefetch ALL layer-1 A into bf16 registers (32x16B loads in flight)
    short8 afr[2][8];
#pragma unroll
    for (int rt = 0; rt < 2; ++rt) {
        int row = rowBase + rt * 16 + m;
        row = row < N_NODES ? row : N_NODES - 1;
        const float* xp = X + (size_t)row * 256 + quad * 8;
#pragma unroll
        for (int kk = 0; kk < 8; ++kk) {
            floatx4 a0 = *(const floatx4*)(xp + kk * 32);
            floatx4 a1 = *(const floatx4*)(xp + kk * 32 + 4);
            short8 v;
            v[0] = (short)f2bf(a0[0]); v[1] = (short)f2bf(a0[1]);
            v[2] = (short)f2bf(a0[2]); v[3] = (short)f2bf(a0[3]);
            v[4] = (short)f2bf(a1[0]); v[5] = (short)f2bf(a1[1]);
            v[6] = (short)f2bf(a1[2]); v[7] = (short)f2bf(a1[3]);
            afr[rt][kk] = v;
        }
    }

    floatx4 acc[2][8];
#pragma unroll
    for (int rt = 0; rt < 2; ++rt)
#pragma unroll
        for (int ct = 0; ct < 8; ++ct) acc[rt][ct] = (floatx4)0.f;

    // ================= Layer 1: x(256) -> h1(128) =================
    // FULLY UNROLLED k-block loop: afr indices stay compile-time constant.
#pragma unroll
    for (int kb4 = 0; kb4 < 4; ++kb4) {
        // stage W1[:, kb4*64 .. +64) as bf16, swizzled
#pragma unroll
        for (int j = 0; j < 8; ++j) {
            int flat = j * 256 + t;
            int n  = flat >> 4;
            int c4 = (flat & 15) * 4;
            floatx4 v = *(const floatx4*)&W1[(size_t)n * 256 + kb4 * 64 + c4];
            *(uint2*)&Wl[n * 64 + (c4 ^ ((n & 7) << 3))] =
                make_uint2(pk2(v[0], v[1]), pk2(v[2], v[3]));
        }
        __syncthreads();
#pragma unroll
        for (int ks = 0; ks < 2; ++ks) {
#pragma unroll
            for (int ct = 0; ct < 8; ++ct) {
                short8 bf = *(const short8*)
                    &Wl[(ct * 16 + m) * 64 + ((ks * 32 + quad * 8) ^ swm)];
                acc[0][ct] = __builtin_amdgcn_mfma_f32_16x16x32_bf16(
                    afr[0][kb4 * 2 + ks], bf, acc[0][ct], 0, 0, 0);
                acc[1][ct] = __builtin_amdgcn_mfma_f32_16x16x32_bf16(
                    afr[1][kb4 * 2 + ks], bf, acc[1][ct], 0, 0, 0);
            }
        }
        __syncthreads();
    }

    // h1 = relu(acc + b1) -> Hb (bf16, swizzled). Each wave owns its 32 rows.
    {
        float br[8];
#pragma unroll
        for (int ct = 0; ct < 8; ++ct) br[ct] = B1[ct * 16 + m];
#pragma unroll
        for (int rt = 0; rt < 2; ++rt)
#pragma unroll
            for (int r = 0; r < 4; ++r) {
                int lrow = w * 32 + rt * 16 + quad * 4 + r;
                int sw = (lrow & 7) << 3;
#pragma unroll
                for (int ct = 0; ct < 8; ++ct) {
                    float v = acc[rt][ct][r] + br[ct];
                    v = v > 0.f ? v : 0.f;
                    Hb[lrow * 128 + ((ct * 16 + m) ^ sw)] = f2bf(v);
                }
            }
    }

#pragma unroll
    for (int rt = 0; rt < 2; ++rt)
#pragma unroll
        for (int ct = 0; ct < 8; ++ct) acc[rt][ct] = (floatx4)0.f;

    // ================= Layer 2: h1(128) -> h2(128) =================
#pragma unroll
    for (int kb2 = 0; kb2 < 2; ++kb2) {
#pragma unroll
        for (int j = 0; j < 8; ++j) {
            int flat = j * 256 + t;
            int n  = flat >> 4;
            int c4 = (flat & 15) * 4;
            floatx4 v = *(const floatx4*)&W2[(size_t)n * 128 + kb2 * 64 + c4];
            *(uint2*)&Wl[n * 64 + (c4 ^ ((n & 7) << 3))] =
                make_uint2(pk2(v[0], v[1]), pk2(v[2], v[3]));
        }
        __syncthreads();   // also makes this wave's Hb writes safely ordered
#pragma unroll
        for (int ks = 0; ks < 2; ++ks) {
            short8 af[2];
#pragma unroll
            for (int rt = 0; rt < 2; ++rt) {
                int lrow = w * 32 + rt * 16 + m;
                int col  = kb2 * 64 + ks * 32 + quad * 8;
                af[rt] = *(const short8*)&Hb[lrow * 128 + (col ^ swm)];
            }
#pragma unroll
            for (int ct = 0; ct < 8; ++ct) {
                short8 bf = *(const short8*)
                    &Wl[(ct * 16 + m) * 64 + ((ks * 32 + quad * 8) ^ swm)];
                acc[0][ct] = __builtin_amdgcn_mfma_f32_16x16x32_bf16(
                    af[0], bf, acc[0][ct], 0, 0, 0);
                acc[1][ct] = __builtin_amdgcn_mfma_f32_16x16x32_bf16(
                    af[1], bf, acc[1][ct], 0, 0, 0);
            }
        }
        __syncthreads();
    }

    // h2 = relu(acc + b2) -> Hb (overwrite own rows; reads drained by barrier)
    {
        float br[8];
#pragma unroll
        for (int ct = 0; ct < 8; ++ct) br[ct] = B2[ct * 16 + m];
#pragma unroll
        for (int rt = 0; rt < 2; ++rt)
#pragma unroll
            for (int r = 0; r < 4; ++r) {
                int lrow = w * 32 + rt * 16 + quad * 4 + r;
                int sw = (lrow & 7) << 3;
#pragma unroll
                for (int ct = 0; ct < 8; ++ct) {
                    float v = acc[rt][ct][r] + br[ct];
                    v = v > 0.f ? v : 0.f;
                    Hb[lrow * 128 + ((ct * 16 + m) ^ sw)] = f2bf(v);
                }
            }
    }

    // ================= Layer 3: h2(128) -> h3(16) =================
    // stage all of W3 (16 x 128) bf16, swizzled
#pragma unroll
    for (int j = 0; j < 2; ++j) {
        int flat = j * 256 + t;
        int n  = flat >> 5;          // 0..15
        int c4 = (flat & 31) * 4;    // 0..124
        floatx4 v = *(const floatx4*)&W3[(size_t)n * 128 + c4];
        *(uint2*)&Wl[n * 128 + (c4 ^ ((n & 7) << 3))] =
            make_uint2(pk2(v[0], v[1]), pk2(v[2], v[3]));
    }
    __syncthreads();

    floatx4 acc3[2];
    acc3[0] = (floatx4)0.f; acc3[1] = (floatx4)0.f;
#pragma unroll
    for (int ks4 = 0; ks4 < 4; ++ks4) {
        int col = ks4 * 32 + quad * 8;
        short8 bf = *(const short8*)&Wl[m * 128 + (col ^ swm)];
#pragma unroll
        for (int rt = 0; rt < 2; ++rt) {
            int lrow = w * 32 + rt * 16 + m;
            short8 af = *(const short8*)&Hb[lrow * 128 + (col ^ swm)];
            acc3[rt] = __builtin_amdgcn_mfma_f32_16x16x32_bf16(
                af, bf, acc3[rt], 0, 0, 0);
        }
    }

    // ---- epilogue: h3 = relu(acc3+b3) -> hops[0] (scoring in combine_all)
    const float b3m = B3[m];
#pragma unroll
    for (int rt = 0; rt < 2; ++rt)
#pragma unroll
        for (int r = 0; r < 4; ++r) {
            int row = rowBase + rt * 16 + quad * 4 + r;
            float v = acc3[rt][r] + b3m;
            v = v > 0.f ? v : 0.f;
            if (row < N_NODES) H0[(size_t)row * 16 + m] = f2bf(v);
        }
}

// ---------------------------------------------------------------------------
// CSR stage 1: per-chunk per-partition histogram -> cmat[p*NCHUNK + chunk]
// ---------------------------------------------------------------------------
__global__ __launch_bounds__(256) void hist2(
    const int* __restrict__ dst, int* __restrict__ cmat)
{
    __shared__ int lhist[NPART];
    const int t = threadIdx.x;
    for (int p = t; p < NPART; p += 256) lhist[p] = 0;
    __syncthreads();
    const int base = blockIdx.x * CHUNK;
#pragma unroll
    for (int j = 0; j < EPT; ++j) {
        int i = base + j * 256 + t;
        if (i < E_EDGES) atomicAdd(&lhist[dst[i] >> 8], 1);
    }
    __syncthreads();
    for (int p = t; p < NPART; p += 256)
        cmat[p * NCHUNK + blockIdx.x] = lhist[p];
}

// ---------------------------------------------------------------------------
// Scan level A: per-8192-segment reduction -> bsum
// ---------------------------------------------------------------------------
__global__ __launch_bounds__(1024) void scan_reduce(
    const int* __restrict__ cmat, int* __restrict__ bsum)
{
    __shared__ int wsum[16];
    const int t = threadIdx.x, lane = t & 63, wid = t >> 6;
    int base = blockIdx.x * SSEG + t * 8;
    int s = 0;
#pragma unroll
    for (int j = 0; j < 8; ++j) {
        int idx = base + j;
        if (idx < NFLAT) s += cmat[idx];
    }
#pragma unroll
    for (int d = 1; d < 64; d <<= 1) s += __shfl_xor(s, d);
    if (lane == 0) wsum[wid] = s;
    __syncthreads();
    if (t == 0) {
        int tot = 0;
#pragma unroll
        for (int i = 0; i < 16; ++i) tot += wsum[i];
        bsum[blockIdx.x] = tot;
    }
}

// ---------------------------------------------------------------------------
// Scan level B: exclusive scan of GA block sums (single wave)
// ---------------------------------------------------------------------------
__global__ void scan_tops(const int* __restrict__ bsum, int* __restrict__ boff)
{
    const int t = threadIdx.x;
    int v = (t < GA) ? bsum[t] : 0;
    int x = v;
#pragma unroll
    for (int d = 1; d < 64; d <<= 1) {
        int y = __shfl_up(x, d);
        if (t >= d) x += y;
    }
    if (t < GA) boff[t] = x - v;
}

// ---------------------------------------------------------------------------
// Scan level C: full exclusive scan applied in-place; also emits pbase[].
// ---------------------------------------------------------------------------
__global__ __launch_bounds__(1024) void scan_apply(
    int* __restrict__ cmat, const int* __restrict__ boff, int* __restrict__ pbase)
{
    __shared__ int wsum[16];
    __shared__ int woff[17];
    const int t = threadIdx.x, lane = t & 63, wid = t >> 6;
    int base = blockIdx.x * SSEG + t * 8;
    int v[8], pre[8];
    int s = 0;
#pragma unroll
    for (int j = 0; j < 8; ++j) {
        int idx = base + j;
        v[j] = (idx < NFLAT) ? cmat[idx] : 0;
        pre[j] = s;
        s += v[j];
    }
    int x = s;
#pragma unroll
    for (int d = 1; d < 64; d <<= 1) {
        int y = __shfl_up(x, d);
        if (lane >= d) x += y;
    }
    if (lane == 63) wsum[wid] = x;
    __syncthreads();
    if (wid == 0) {
        int w = (lane < 16) ? wsum[lane] : 0;
#pragma unroll
        for (int d = 1; d < 16; d <<= 1) {
            int y = __shfl_up(w, d);
            if (lane >= d) w += y;
        }
        if (lane < 16) woff[lane + 1] = w;
        if (lane == 0) woff[0] = 0;
    }
    __syncthreads();
    int tbase = boff[blockIdx.x] + woff[wid] + (x - s);
#pragma unroll
    for (int j = 0; j < 8; ++j) {
        int idx = base + j;
        if (idx < NFLAT) {
            int e = tbase + pre[j];
            cmat[idx] = e;
            if (idx % NCHUNK == 0) pbase[idx / NCHUNK] = e;
        }
    }
    if (blockIdx.x == 0 && t == 0) pbase[NPART] = E_EDGES;
}

// ---------------------------------------------------------------------------
// CSR stage 2: LDS-sorted scatter.
// ---------------------------------------------------------------------------
__global__ __launch_bounds__(256) void scatter3(
    const int* __restrict__ src, const int* __restrict__ dst,
    const float* __restrict__ ea, const int* __restrict__ cbase,
    int2* __restrict__ staging)
{
    __shared__ int2 ebuf[CHUNK];     // 32 KB sorted entries
    __shared__ int  gaddr[CHUNK];    // 16 KB global positions
    __shared__ int  lcnt[NPART];     // counts -> cursors (local sorted idx)
    __shared__ int  goff[NPART];     // global pos = goff[p] + local idx
    __shared__ int  wsum[4];
    const int t = threadIdx.x;
    const int b = blockIdx.x;
    const int base = b * CHUNK;
    const int cnt = min(CHUNK, E_EDGES - base);
    const int lane = t & 63, wid = t >> 6;

    for (int p = t; p < NPART; p += 256) lcnt[p] = 0;
    __syncthreads();

    int d[EPT];
#pragma unroll
    for (int j = 0; j < EPT; ++j) {
        int i = base + j * 256 + t;
        d[j] = (i < E_EDGES) ? dst[i] : -1;
        if (d[j] >= 0) atomicAdd(&lcnt[d[j] >> 8], 1);
    }
    __syncthreads();

    int v0 = (2 * t     < NPART) ? lcnt[2 * t]     : 0;
    int v1 = (2 * t + 1 < NPART) ? lcnt[2 * t + 1] : 0;
    int pair = v0 + v1;
    int x = pair;
#pragma unroll
    for (int dd = 1; dd < 64; dd <<= 1) {
        int y = __shfl_up(x, dd);
        if (lane >= dd) x += y;
    }
    if (lane == 63) wsum[wid] = x;
    __syncthreads();
    int wbase = 0;
#pragma unroll
    for (int w = 0; w < 4; ++w) if (w < wid) wbase += wsum[w];
    int excl = wbase + x - pair;
    if (2 * t < NPART) {
        lcnt[2 * t] = excl;
        goff[2 * t] = cbase[(2 * t) * NCHUNK + b] - excl;
    }
    if (2 * t + 1 < NPART) {
        lcnt[2 * t + 1] = excl + v0;
        goff[2 * t + 1] = cbase[(2 * t + 1) * NCHUNK + b] - (excl + v0);
    }
    __syncthreads();

#pragma unroll
    for (int j = 0; j < EPT; ++j) {
        if (d[j] >= 0) {
            int i = base + j * 256 + t;
            int p = d[j] >> 8;
            int s = atomicAdd(&lcnt[p], 1);
            ebuf[s]  = make_int2(__float_as_int(ea[i]),
                                 src[i] | ((d[j] & 255) << 17));
            gaddr[s] = goff[p] + s;
        }
    }
    __syncthreads();

    for (int k = t; k < cnt; k += 256)
        staging[gaddr[k]] = ebuf[k];
}

// ---------------------------------------------------------------------------
// CSR stage 3: one 1024-thread block per partition -> rowp + final CSR.
// ---------------------------------------------------------------------------
__global__ __launch_bounds__(1024) void partition_build(
    const int2* __restrict__ staging, const int* __restrict__ pbase,
    int* __restrict__ rowp, int2* __restrict__ csr)
{
    __shared__ int ncnt[NPP];
    __shared__ int wsum[4];
    const int p = blockIdx.x;
    const int t = threadIdx.x;
    const int e0 = pbase[p], e1 = pbase[p + 1];
    const int cnt = e1 - e0;
    const int n0 = p << 8;

    if (t < NPP) ncnt[t] = 0;
    __syncthreads();
    for (int e = t; e < cnt; e += 1024)
        atomicAdd(&ncnt[(staging[e0 + e].y >> 17) & 255], 1);
    __syncthreads();

    int x = 0, v = 0;
    if (t < NPP) {
        const int lane = t & 63, wid = t >> 6;
        v = ncnt[t];
        x = v;
#pragma unroll
        for (int d = 1; d < 64; d <<= 1) {
            int y = __shfl_up(x, d);
            if (lane >= d) x += y;
        }
        if (lane == 63) wsum[wid] = x;
    }
    __syncthreads();
    if (t < NPP) {
        const int wid = t >> 6;
        int wbase = 0;
#pragma unroll
        for (int w = 0; w < 4; ++w) if (w < wid) wbase += wsum[w];
        int excl = wbase + x - v;
        ncnt[t] = e0 + excl;
        int n = n0 + t;
        if (n < N_NODES) rowp[n] = e0 + excl;
    }
    if (p == NPART - 1 && t == 0) rowp[N_NODES] = E_EDGES;
    __syncthreads();

    for (int e = t; e < cnt; e += 1024) {
        int2 en = staging[e0 + e];
        int dlo = (en.y >> 17) & 255;
        int pos = atomicAdd(&ncnt[dlo], 1);
        csr[pos] = make_int2(en.y & 0x1FFFF, en.x);
    }
}

// ---------------------------------------------------------------------------
// One hop (bf16 states), gather only. 8 lanes/node, 4 gathers in flight.
// r5-EXACT form (plain loads). Verified best: ~43us/hop. Failed variants:
// r4 8-deep ILP (null), r6 LDS-atomic (7x worse), r9 nt (+25%), r11
// nt+prefetch (+20%). The hop is at its divergent-gather HW floor for
// bf16 states; do not re-tune the load path.
// ---------------------------------------------------------------------------
__global__ __launch_bounds__(256) void hop_bf16(
    const ushort* __restrict__ prev, ushort* __restrict__ next,
    const int* __restrict__ rowp, const int2* __restrict__ csr)
{
    const int t = threadIdx.x;
    const int l = t & 1;
    const int g = (t >> 1) & 3;
    const int n = blockIdx.x * 32 + (t >> 3);
    if (n >= N_NODES) return;
    const int e0 = rowp[n], e1 = rowp[n + 1];
    float a[8];
#pragma unroll
    for (int j = 0; j < 8; ++j) a[j] = 0.f;

    int e = e0 + g;
    for (; e + 12 < e1; e += 16) {
        int2 c0 = csr[e];
        int2 c1 = csr[e + 4];
        int2 c2 = csr[e + 8];
        int2 c3 = csr[e + 12];
        float w0 = __int_as_float(c0.y), w1 = __int_as_float(c1.y);
        float w2 = __int_as_float(c2.y), w3 = __int_as_float(c3.y);
        uint4 v0 = *(const uint4*)&prev[(size_t)c0.x * 16 + l * 8];
        uint4 v1 = *(const uint4*)&prev[(size_t)c1.x * 16 + l * 8];
        uint4 v2 = *(const uint4*)&prev[(size_t)c2.x * 16 + l * 8];
        uint4 v3 = *(const uint4*)&prev[(size_t)c3.x * 16 + l * 8];
        a[0] += w0 * bflo(v0.x); a[1] += w0 * bfhi(v0.x);
        a[2] += w0 * bflo(v0.y); a[3] += w0 * bfhi(v0.y);
        a[4] += w0 * bflo(v0.z); a[5] += w0 * bfhi(v0.z);
        a[6] += w0 * bflo(v0.w); a[7] += w0 * bfhi(v0.w);
        a[0] += w1 * bflo(v1.x); a[1] += w1 * bfhi(v1.x);
        a[2] += w1 * bflo(v1.y); a[3] += w1 * bfhi(v1.y);
        a[4] += w1 * bflo(v1.z); a[5] += w1 * bfhi(v1.z);
        a[6] += w1 * bflo(v1.w); a[7] += w1 * bfhi(v1.w);
        a[0] += w2 * bflo(v2.x); a[1] += w2 * bfhi(v2.x);
        a[2] += w2 * bflo(v2.y); a[3] += w2 * bfhi(v2.y);
        a[4] += w2 * bflo(v2.z); a[5] += w2 * bfhi(v2.z);
        a[6] += w2 * bflo(v2.w); a[7] += w2 * bfhi(v2.w);
        a[0] += w3 * bflo(v3.x); a[1] += w3 * bfhi(v3.x);
        a[2] += w3 * bflo(v3.y); a[3] += w3 * bfhi(v3.y);
        a[4] += w3 * bflo(v3.z); a[5] += w3 * bfhi(v3.z);
        a[6] += w3 * bflo(v3.w); a[7] += w3 * bfhi(v3.w);
    }
    for (; e < e1; e += 4) {
        int2 c0 = csr[e];
        float w0 = __int_as_float(c0.y);
        uint4 v0 = *(const uint4*)&prev[(size_t)c0.x * 16 + l * 8];
        a[0] += w0 * bflo(v0.x); a[1] += w0 * bfhi(v0.x);
        a[2] += w0 * bflo(v0.y); a[3] += w0 * bfhi(v0.y);
        a[4] += w0 * bflo(v0.z); a[5] += w0 * bfhi(v0.z);
        a[6] += w0 * bflo(v0.w); a[7] += w0 * bfhi(v0.w);
    }

#pragma unroll
    for (int d = 2; d <= 4; d <<= 1) {
#pragma unroll
        for (int j = 0; j < 8; ++j) a[j] += __shfl_xor(a[j], d);
    }

    if (g == 0) {
        uint4 nv = make_uint4(pk2(a[0], a[1]), pk2(a[2], a[3]),
                              pk2(a[4], a[5]), pk2(a[6], a[7]));
        *(uint4*)&next[(size_t)n * 16 + l * 8] = nv;
    }
}

// ---------------------------------------------------------------------------
// Final combine: out[n] = sum_k sigmoid(hops[k][n].pw + pb) * hops[k][n].
// 2 lanes/node, 11 independent 16B loads in flight per lane.
// ---------------------------------------------------------------------------
__global__ __launch_bounds__(256) void combine_all(
    const ushort* __restrict__ hops,   // (K+1) buffers, stride N*16
    const float* __restrict__ pw, const float* __restrict__ pb,
    float* __restrict__ out)
{
    const int t = threadIdx.x;
    const int l = t & 1;
    const int n = blockIdx.x * 128 + (t >> 1);
    if (n >= N_NODES) return;
    float4 p0 = ((const float4*)pw)[l * 2];
    float4 p1 = ((const float4*)pw)[l * 2 + 1];
    const float pb0 = pb[0];
    float o0 = 0.f, o1 = 0.f, o2 = 0.f, o3 = 0.f;
    float o4 = 0.f, o5 = 0.f, o6 = 0.f, o7 = 0.f;
#pragma unroll
    for (int k = 0; k <= K_HOPS; ++k) {
        uint4 v = *(const uint4*)
            &hops[((size_t)k * N_NODES + n) * 16 + l * 8];
        float a0 = bflo(v.x), a1 = bfhi(v.x), a2 = bflo(v.y), a3 = bfhi(v.y);
        float a4 = bflo(v.z), a5 = bfhi(v.z), a6 = bflo(v.w), a7 = bfhi(v.w);
        float part = a0*p0.x + a1*p0.y + a2*p0.z + a3*p0.w
                   + a4*p1.x + a5*p1.y + a6*p1.z + a7*p1.w;
        part += __shfl_xor(part, 1);
        float s = 1.f / (1.f + __expf(-(part + pb0)));
        o0 += s*a0; o1 += s*a1; o2 += s*a2; o3 += s*a3;
        o4 += s*a4; o5 += s*a5; o6 += s*a6; o7 += s*a7;
    }
    *(float4*)&out[(size_t)n * 16 + l * 8]     = make_float4(o0, o1, o2, o3);
    *(float4*)&out[(size_t)n * 16 + l * 8 + 4] = make_float4(o4, o5, o6, o7);
}

// ---------------------------------------------------------------------------
extern "C" void kernel_launch(void* const* d_in, const int* in_sizes, int n_in,
                              void* d_out, int out_size, void* d_ws, size_t ws_size,
                              hipStream_t stream)
{
    const float* x  = (const float*)d_in[0];
    const int*   ei = (const int*)d_in[1];
    const float* ea = (const float*)d_in[2];
    const float* w1 = (const float*)d_in[3];
    const float* b1 = (const float*)d_in[4];
    const float* w2 = (const float*)d_in[5];
    const float* b2 = (const float*)d_in[6];
    const float* w3 = (const float*)d_in[7];
    const float* b3 = (const float*)d_in[8];
    const float* pw = (const float*)d_in[9];
    const float* pb = (const float*)d_in[10];
    float* out = (float*)d_out;

    char* ws = (char*)d_ws;
    size_t off = 0;
    char*   region0 = ws + off;           off += (size_t)E_EDGES * 16;       // 51.2 MB
    int*    rowp  = (int*)(ws + off);     off += (((size_t)(N_NODES + 1) * 4) + 15) & ~(size_t)15;
    int*    cmat  = (int*)(ws + off);     off += ((size_t)NFLAT * 4 + 15) & ~(size_t)15;  // 1.22 MB
    int*    bsum  = (int*)(ws + off);     off += ((size_t)GA * 4 + 15) & ~(size_t)15;
    int*    boff  = (int*)(ws + off);     off += ((size_t)GA * 4 + 15) & ~(size_t)15;
    int*    pbase = (int*)(ws + off);     off += ((size_t)(NPART + 1) * 4 + 15) & ~(size_t)15;
    int2*   csr   = (int2*)(ws + off);    off += (size_t)E_EDGES * 8;        // 25.6 MB

    // staging (25.6MB) lives in region0 during CSR build; afterwards region0
    // holds the 11 hop-state buffers (11 x 3.2MB = 35.2MB <= 51.2MB).
    // Stream-ordered: partition_build finishes staging reads before
    // fused_mlp writes hops[0].
    int2*   staging = (int2*)region0;
    ushort* hops    = (ushort*)region0;
    const size_t HSTRIDE = (size_t)N_NODES * 16;   // ushorts per hop buffer

    const int* src = ei;
    const int* dst = ei + E_EDGES;

    const dim3 blk(256);
    const int mlpGrid    = (N_NODES + 127) / 128;   // 782
    const int hopGrid    = (N_NODES + 31) / 32;     // 3125

    // ---- CSR build: contention-free multi-split ----
    hist2<<<NCHUNK, blk, 0, stream>>>(dst, cmat);
    scan_reduce<<<GA, 1024, 0, stream>>>(cmat, bsum);
    scan_tops<<<1, 64, 0, stream>>>(bsum, boff);
    scan_apply<<<GA, 1024, 0, stream>>>(cmat, boff, pbase);
    scatter3<<<NCHUNK, blk, 0, stream>>>(src, dst, ea, cmat, staging);
    partition_build<<<NPART, 1024, 0, stream>>>(staging, pbase, rowp, csr);

    // ---- fused MLP (3 layers) -> hops[0] ----
    fused_mlp<<<mlpGrid, blk, 0, stream>>>(x, w1, b1, w2, b2, w3, b3, hops);

    // ---- K hops (gather only, r5-plain load path) ----
    for (int k = 0; k < K_HOPS; ++k) {
        hop_bf16<<<hopGrid, blk, 0, stream>>>(hops + (size_t)k * HSTRIDE,
                                              hops + (size_t)(k + 1) * HSTRIDE,
                                              rowp, csr);
    }

    // ---- final combine over all K+1 states ----
    combine_all<<<mlpGrid, blk, 0, stream>>>(hops, pw, pb, out);
}